// Round 4
// baseline (5279.933 us; speedup 1.0000x reference)
//
#include <hip/hip_runtime.h>
#include <hip/hip_bf16.h>
#include <math.h>

// Problem constants
#define B_    2
#define N_    2048
#define D_    1024
#define NC_   77
#define DC_   768
#define H_    16
#define DH_   64
#define FF_   4096
#define EPS_  1e-5f
#define SCALE_ 0.125f   // DH^-0.5
#define NEG_BIG -1e30f

// ---------- LayerNorm over D=1024, one block (256 thr) per row ----------
__global__ __launch_bounds__(256) void ln_k(const float* __restrict__ x,
                                            const float* __restrict__ g,
                                            const float* __restrict__ b,
                                            float* __restrict__ out) {
    int row = blockIdx.x;
    const float* xr = x + (size_t)row * D_;
    float v0[4]; float s = 0.f, sq = 0.f;
#pragma unroll
    for (int i = 0; i < 4; i++) {
        float t = xr[threadIdx.x + 256 * i];
        v0[i] = t; s += t; sq += t * t;
    }
#pragma unroll
    for (int off = 32; off; off >>= 1) {
        s  += __shfl_xor(s,  off);
        sq += __shfl_xor(sq, off);
    }
    __shared__ float rs[4], rq[4];
    int wave = threadIdx.x >> 6, lane = threadIdx.x & 63;
    if (lane == 0) { rs[wave] = s; rq[wave] = sq; }
    __syncthreads();
    s  = rs[0] + rs[1] + rs[2] + rs[3];
    sq = rq[0] + rq[1] + rq[2] + rq[3];
    float mu  = s * (1.f / D_);
    float var = sq * (1.f / D_) - mu * mu;
    float inv = rsqrtf(var + EPS_);
#pragma unroll
    for (int i = 0; i < 4; i++) {
        int c = threadIdx.x + 256 * i;
        out[(size_t)row * D_ + c] = (v0[i] - mu) * inv * g[c] + b[c];
    }
}

// ---------- generic tiled GEMM: C[M,N] = A[M,K](f32) @ W[K,N](f32) (+bias)(+res) ----------
// BM=BN=64, BK=16, 256 threads, 4x4 micro-tile per thread. f32 output.
__global__ __launch_bounds__(256) void gemm_k(const float* __restrict__ A,
                                              const float* __restrict__ W,
                                              const float* __restrict__ bias,
                                              const float* __restrict__ res,
                                              float* __restrict__ outf,
                                              int M, int N, int K) {
    __shared__ float As[16][64];   // [k][m]
    __shared__ float Ws[16][64];   // [k][n]
    const int tx = threadIdx.x & 15;   // col group
    const int ty = threadIdx.x >> 4;   // row group
    const int m0 = blockIdx.y * 64, n0 = blockIdx.x * 64;
    const int lm = threadIdx.x >> 2;         // 0..63 (A row in tile)
    const int lk = (threadIdx.x & 3) * 4;    // 0,4,8,12
    const int wr = threadIdx.x >> 4;         // 0..15 (W row in tile)
    const int wc = (threadIdx.x & 15) * 4;   // 0..60
    float acc[4][4] = {};
    for (int k0 = 0; k0 < K; k0 += 16) {
        float4 av = make_float4(0.f, 0.f, 0.f, 0.f);
        if (m0 + lm < M) av = *(const float4*)&A[(size_t)(m0 + lm) * K + k0 + lk];
        float4 wv = *(const float4*)&W[(size_t)(k0 + wr) * N + n0 + wc];
        As[lk + 0][lm] = av.x; As[lk + 1][lm] = av.y;
        As[lk + 2][lm] = av.z; As[lk + 3][lm] = av.w;
        *(float4*)&Ws[wr][wc] = wv;
        __syncthreads();
#pragma unroll
        for (int kk = 0; kk < 16; kk++) {
            float4 a = *(const float4*)&As[kk][ty * 4];
            float4 b = *(const float4*)&Ws[kk][tx * 4];
            float ar[4] = { a.x, a.y, a.z, a.w };
            float br[4] = { b.x, b.y, b.z, b.w };
#pragma unroll
            for (int i = 0; i < 4; i++)
#pragma unroll
                for (int j = 0; j < 4; j++)
                    acc[i][j] = fmaf(ar[i], br[j], acc[i][j]);
        }
        __syncthreads();
    }
#pragma unroll
    for (int i = 0; i < 4; i++) {
        int row = m0 + ty * 4 + i;
        if (row >= M) continue;
#pragma unroll
        for (int j = 0; j < 4; j++) {
            int col = n0 + tx * 4 + j;
            float c = acc[i][j];
            if (bias) c += bias[col];
            if (res)  c += res[(size_t)row * N + col];
            outf[(size_t)row * N + col] = c;
        }
    }
}

// ---------- fused GEGLU GEMM: out[M,4096] = (A@W[:, :FF]+b_v) * gelu(A@W[:, FF:]+b_g) ----------
__global__ __launch_bounds__(256) void geglu_k(const float* __restrict__ A,
                                               const float* __restrict__ W,     // [K, 2*FF]
                                               const float* __restrict__ bias,  // [2*FF]
                                               float* __restrict__ out, int M, int K) {
    const int N2 = 2 * FF_;
    __shared__ float As[16][64];
    __shared__ float Wv[16][64];
    __shared__ float Wg[16][64];
    const int tx = threadIdx.x & 15;
    const int ty = threadIdx.x >> 4;
    const int m0 = blockIdx.y * 64, n0 = blockIdx.x * 64;
    const int lm = threadIdx.x >> 2;
    const int lk = (threadIdx.x & 3) * 4;
    const int wr = threadIdx.x >> 4;
    const int wc = (threadIdx.x & 15) * 4;
    float accv[4][4] = {}, accg[4][4] = {};
    for (int k0 = 0; k0 < K; k0 += 16) {
        float4 av = make_float4(0.f, 0.f, 0.f, 0.f);
        if (m0 + lm < M) av = *(const float4*)&A[(size_t)(m0 + lm) * K + k0 + lk];
        float4 wv = *(const float4*)&W[(size_t)(k0 + wr) * N2 + n0 + wc];
        float4 wg = *(const float4*)&W[(size_t)(k0 + wr) * N2 + n0 + wc + FF_];
        As[lk + 0][lm] = av.x; As[lk + 1][lm] = av.y;
        As[lk + 2][lm] = av.z; As[lk + 3][lm] = av.w;
        *(float4*)&Wv[wr][wc] = wv;
        *(float4*)&Wg[wr][wc] = wg;
        __syncthreads();
#pragma unroll
        for (int kk = 0; kk < 16; kk++) {
            float4 a  = *(const float4*)&As[kk][ty * 4];
            float4 bv = *(const float4*)&Wv[kk][tx * 4];
            float4 bg = *(const float4*)&Wg[kk][tx * 4];
            float ar[4]  = { a.x, a.y, a.z, a.w };
            float bvr[4] = { bv.x, bv.y, bv.z, bv.w };
            float bgr[4] = { bg.x, bg.y, bg.z, bg.w };
#pragma unroll
            for (int i = 0; i < 4; i++)
#pragma unroll
                for (int j = 0; j < 4; j++) {
                    accv[i][j] = fmaf(ar[i], bvr[j], accv[i][j]);
                    accg[i][j] = fmaf(ar[i], bgr[j], accg[i][j]);
                }
        }
        __syncthreads();
    }
#pragma unroll
    for (int i = 0; i < 4; i++) {
        int row = m0 + ty * 4 + i;
        if (row >= M) continue;
#pragma unroll
        for (int j = 0; j < 4; j++) {
            int col = n0 + tx * 4 + j;
            float vv = accv[i][j] + bias[col];
            float gg = accg[i][j] + bias[col + FF_];
            float gelu = 0.5f * gg * (1.f + erff(gg * 0.70710678118654752f));
            out[(size_t)row * FF_ + col] = vv * gelu;
        }
    }
}

// ---------- flash attention: one wave per query row, 64-key LDS tiles ----------
// q: [B, N_, D_] f32 (head h at cols h*64..), k/v: [B, n_kv, D_] f32, o: [B, N_, D_]
__global__ __launch_bounds__(256) void flash_k(const float* __restrict__ q,
                                               const float* __restrict__ k,
                                               const float* __restrict__ v,
                                               float* __restrict__ o, int n_kv) {
    __shared__ float kt[64][DH_ + 4];
    __shared__ float vt[64][DH_ + 4];
    __shared__ float qs[4][DH_];
    __shared__ float ps[4][64];
    const int bh = blockIdx.x;              // b*H + h
    const int bb = bh / H_, hh = bh % H_;
    const int wave = threadIdx.x >> 6, lane = threadIdx.x & 63;
    const int qi = blockIdx.y * 4 + wave;
    const size_t qoff = ((size_t)(bb * N_ + qi)) * D_ + hh * DH_;
    qs[wave][lane] = q[qoff + lane];
    float m = NEG_BIG, l = 0.f, acc = 0.f;
    for (int j0 = 0; j0 < n_kv; j0 += 64) {
        for (int idx = threadIdx.x; idx < 64 * DH_; idx += 256) {
            int jj = idx >> 6, d = idx & 63;
            int jg = j0 + jj;
            float kv_ = 0.f, vv_ = 0.f;
            if (jg < n_kv) {
                size_t off = ((size_t)(bb * n_kv + jg)) * D_ + hh * DH_ + d;
                kv_ = k[off]; vv_ = v[off];
            }
            kt[jj][d] = kv_; vt[jj][d] = vv_;
        }
        __syncthreads();
        float s;
        if (j0 + lane < n_kv) {
            s = 0.f;
            const float4* kr = (const float4*)&kt[lane][0];
            const float4* qr = (const float4*)&qs[wave][0];
#pragma unroll
            for (int d = 0; d < 16; d++) {
                float4 k4 = kr[d], q4 = qr[d];
                s += k4.x * q4.x + k4.y * q4.y + k4.z * q4.z + k4.w * q4.w;
            }
            s *= SCALE_;
        } else s = NEG_BIG;
        float tm = s;
#pragma unroll
        for (int off = 32; off; off >>= 1) tm = fmaxf(tm, __shfl_xor(tm, off));
        float mn = fmaxf(m, tm);
        float alpha = __expf(m - mn);     // first tile: exp(-1e30) -> 0
        float p = __expf(s - mn);         // masked lanes -> 0
        float tl = p;
#pragma unroll
        for (int off = 32; off; off >>= 1) tl += __shfl_xor(tl, off);
        l = l * alpha + tl;
        ps[wave][lane] = p;
        float a2 = 0.f;
#pragma unroll 8
        for (int j = 0; j < 64; j++) a2 = fmaf(ps[wave][j], vt[j][lane], a2);
        acc = acc * alpha + a2;
        m = mn;
        __syncthreads();
    }
    o[qoff + lane] = acc / l;
}

// ---------- host ----------
extern "C" void kernel_launch(void* const* d_in, const int* in_sizes, int n_in,
                              void* d_out, int out_size, void* d_ws, size_t ws_size,
                              hipStream_t stream) {
    const float* x_in  = (const float*)d_in[0];
    const float* ctx_in= (const float*)d_in[1];
    const float* w1q = (const float*)d_in[2];
    const float* w1k = (const float*)d_in[3];
    const float* w1v = (const float*)d_in[4];
    const float* w1o = (const float*)d_in[5];
    const float* b1o = (const float*)d_in[6];
    const float* w2q = (const float*)d_in[7];
    const float* w2k = (const float*)d_in[8];
    const float* w2v = (const float*)d_in[9];
    const float* w2o = (const float*)d_in[10];
    const float* b2o = (const float*)d_in[11];
    const float* ln1g= (const float*)d_in[12];
    const float* ln1b= (const float*)d_in[13];
    const float* ln2g= (const float*)d_in[14];
    const float* ln2b= (const float*)d_in[15];
    const float* ln3g= (const float*)d_in[16];
    const float* ln3b= (const float*)d_in[17];
    const float* ffw1= (const float*)d_in[18];
    const float* ffb1= (const float*)d_in[19];
    const float* ffw2= (const float*)d_in[20];
    const float* ffb2= (const float*)d_in[21];
    float* out_f = (float*)d_out;   // reference output dtype is float32

    // ws arena (f32), 96 MB total:
    // xbuf[0,16M) h[16,32M) q[32,48M) k[48,64M) v[64,80M) o[80,96M)
    // g[32,96M) overlaps q..o (they are dead during FF phase).
    char* ws = (char*)d_ws;
    float* xbuf = (float*)(ws);
    float* h    = (float*)(ws + (size_t)(16 << 20));
    float* q    = (float*)(ws + (size_t)(32 << 20));
    float* k    = (float*)(ws + (size_t)(48 << 20));
    float* v    = (float*)(ws + (size_t)(64 << 20));
    float* o    = (float*)(ws + (size_t)(80 << 20));
    float* g    = (float*)(ws + (size_t)(32 << 20));   // overlaps q,k,v,o

    const int MT = B_ * N_;        // 4096 token rows
    const int MC = B_ * NC_;       // 154 context rows

    auto gemm = [&](const float* A, const float* W, const float* bias,
                    const float* res, float* outf, int M, int N, int K) {
        dim3 grid(N / 64, (M + 63) / 64);
        hipLaunchKernelGGL(gemm_k, grid, dim3(256), 0, stream, A, W, bias, res, outf, M, N, K);
    };

    // ---- self attention ----
    hipLaunchKernelGGL(ln_k, dim3(MT), dim3(256), 0, stream, x_in, ln1g, ln1b, h);
    gemm(h, w1q, nullptr, nullptr, q, MT, D_, D_);
    gemm(h, w1k, nullptr, nullptr, k, MT, D_, D_);
    gemm(h, w1v, nullptr, nullptr, v, MT, D_, D_);
    hipLaunchKernelGGL(flash_k, dim3(B_ * H_, N_ / 4), dim3(256), 0, stream, q, k, v, o, N_);
    gemm(o, w1o, b1o, x_in, xbuf, MT, D_, D_);   // x = attn_out + x_in

    // ---- cross attention ----
    hipLaunchKernelGGL(ln_k, dim3(MT), dim3(256), 0, stream, xbuf, ln2g, ln2b, h);
    gemm(h, w2q, nullptr, nullptr, q, MT, D_, D_);
    gemm(ctx_in, w2k, nullptr, nullptr, k, MC, D_, DC_);
    gemm(ctx_in, w2v, nullptr, nullptr, v, MC, D_, DC_);
    hipLaunchKernelGGL(flash_k, dim3(B_ * H_, N_ / 4), dim3(256), 0, stream, q, k, v, o, NC_);
    gemm(o, w2o, b2o, xbuf, xbuf, MT, D_, D_);

    // ---- feed-forward (GEGLU) ----
    hipLaunchKernelGGL(ln_k, dim3(MT), dim3(256), 0, stream, xbuf, ln3g, ln3b, h);
    hipLaunchKernelGGL(geglu_k, dim3(FF_ / 64, MT / 64), dim3(256), 0, stream, h, ffw1, ffb1, g, MT, D_);
    gemm(g, ffw2, ffb2, xbuf, out_f, MT, D_, FF_);
}

// Round 5
// 2573.074 us; speedup vs baseline: 2.0520x; 2.0520x over previous
//
#include <hip/hip_runtime.h>
#include <hip/hip_bf16.h>
#include <math.h>

// Problem constants
#define B_    2
#define N_    2048
#define D_    1024
#define NC_   77
#define DC_   768
#define H_    16
#define DH_   64
#define FF_   4096
#define EPS_  1e-5f
#define SCALE_ 0.125f   // DH^-0.5
#define NEG_BIG -1e30f

typedef __attribute__((ext_vector_type(8))) short short8;   // 8 bf16 in 4 VGPRs
typedef __attribute__((ext_vector_type(4))) float f32x4;
#define MFMA16(a, b, c) __builtin_amdgcn_mfma_f32_16x16x32_bf16(a, b, c, 0, 0, 0)

// ---------- helpers ----------
static __device__ __forceinline__ unsigned short f2bf_raw(float f) {
    union { float f; unsigned int i; } x; x.f = f;
    unsigned int r = x.i + 0x7fffu + ((x.i >> 16) & 1u);   // RNE
    return (unsigned short)(r >> 16);
}

// ---------- LayerNorm over D=1024, one block (256 thr) per row ----------
__global__ __launch_bounds__(256) void ln_k(const float* __restrict__ x,
                                            const float* __restrict__ g,
                                            const float* __restrict__ b,
                                            float* __restrict__ out) {
    int row = blockIdx.x;
    const float* xr = x + (size_t)row * D_;
    float v0[4]; float s = 0.f, sq = 0.f;
#pragma unroll
    for (int i = 0; i < 4; i++) {
        float t = xr[threadIdx.x + 256 * i];
        v0[i] = t; s += t; sq += t * t;
    }
#pragma unroll
    for (int off = 32; off; off >>= 1) {
        s  += __shfl_xor(s,  off);
        sq += __shfl_xor(sq, off);
    }
    __shared__ float rs[4], rq[4];
    int wave = threadIdx.x >> 6, lane = threadIdx.x & 63;
    if (lane == 0) { rs[wave] = s; rq[wave] = sq; }
    __syncthreads();
    s  = rs[0] + rs[1] + rs[2] + rs[3];
    sq = rq[0] + rq[1] + rq[2] + rq[3];
    float mu  = s * (1.f / D_);
    float var = sq * (1.f / D_) - mu * mu;
    float inv = rsqrtf(var + EPS_);
#pragma unroll
    for (int i = 0; i < 4; i++) {
        int c = threadIdx.x + 256 * i;
        out[(size_t)row * D_ + c] = (v0[i] - mu) * inv * g[c] + b[c];
    }
}

// ---------- generic tiled GEMM: C[M,N] = A[M,K](f32) @ W[K,N](f32) (+bias)(+res) ----------
// BM=BN=64, BK=16, 256 threads, 4x4 micro-tile. outf!=0 -> f32 store; else bf16 (scaled).
__global__ __launch_bounds__(256) void gemm_k(const float* __restrict__ A,
                                              const float* __restrict__ W,
                                              const float* __restrict__ bias,
                                              const float* __restrict__ res,
                                              float* __restrict__ outf,
                                              unsigned short* __restrict__ outb,
                                              float scale,
                                              int M, int N, int K) {
    __shared__ float As[16][64];   // [k][m]
    __shared__ float Ws[16][64];   // [k][n]
    const int tx = threadIdx.x & 15;
    const int ty = threadIdx.x >> 4;
    const int m0 = blockIdx.y * 64, n0 = blockIdx.x * 64;
    const int lm = threadIdx.x >> 2;
    const int lk = (threadIdx.x & 3) * 4;
    const int wr = threadIdx.x >> 4;
    const int wc = (threadIdx.x & 15) * 4;
    float acc[4][4] = {};
    for (int k0 = 0; k0 < K; k0 += 16) {
        float4 av = make_float4(0.f, 0.f, 0.f, 0.f);
        if (m0 + lm < M) av = *(const float4*)&A[(size_t)(m0 + lm) * K + k0 + lk];
        float4 wv = *(const float4*)&W[(size_t)(k0 + wr) * N + n0 + wc];
        As[lk + 0][lm] = av.x; As[lk + 1][lm] = av.y;
        As[lk + 2][lm] = av.z; As[lk + 3][lm] = av.w;
        *(float4*)&Ws[wr][wc] = wv;
        __syncthreads();
#pragma unroll
        for (int kk = 0; kk < 16; kk++) {
            float4 a = *(const float4*)&As[kk][ty * 4];
            float4 b = *(const float4*)&Ws[kk][tx * 4];
            float ar[4] = { a.x, a.y, a.z, a.w };
            float br[4] = { b.x, b.y, b.z, b.w };
#pragma unroll
            for (int i = 0; i < 4; i++)
#pragma unroll
                for (int j = 0; j < 4; j++)
                    acc[i][j] = fmaf(ar[i], br[j], acc[i][j]);
        }
        __syncthreads();
    }
#pragma unroll
    for (int i = 0; i < 4; i++) {
        int row = m0 + ty * 4 + i;
        if (row >= M) continue;
        float cv[4];
#pragma unroll
        for (int j = 0; j < 4; j++) {
            int col = n0 + tx * 4 + j;
            float c = acc[i][j];
            if (bias) c += bias[col];
            if (res)  c += res[(size_t)row * N + col];
            cv[j] = c * scale;
        }
        if (outf) {
            *(float4*)&outf[(size_t)row * N + n0 + tx * 4] =
                make_float4(cv[0], cv[1], cv[2], cv[3]);
        } else {
            ushort4 u;
            u.x = f2bf_raw(cv[0]); u.y = f2bf_raw(cv[1]);
            u.z = f2bf_raw(cv[2]); u.w = f2bf_raw(cv[3]);
            *(ushort4*)&outb[(size_t)row * N + n0 + tx * 4] = u;
        }
    }
}

// ---------- fused GEGLU GEMM: out[M,4096] = (A@W[:, :FF]+b_v) * gelu(A@W[:, FF:]+b_g) ----------
__global__ __launch_bounds__(256) void geglu_k(const float* __restrict__ A,
                                               const float* __restrict__ W,     // [K, 2*FF]
                                               const float* __restrict__ bias,  // [2*FF]
                                               float* __restrict__ out, int M, int K) {
    const int N2 = 2 * FF_;
    __shared__ float As[16][64];
    __shared__ float Wv[16][64];
    __shared__ float Wg[16][64];
    const int tx = threadIdx.x & 15;
    const int ty = threadIdx.x >> 4;
    const int m0 = blockIdx.y * 64, n0 = blockIdx.x * 64;
    const int lm = threadIdx.x >> 2;
    const int lk = (threadIdx.x & 3) * 4;
    const int wr = threadIdx.x >> 4;
    const int wc = (threadIdx.x & 15) * 4;
    float accv[4][4] = {}, accg[4][4] = {};
    for (int k0 = 0; k0 < K; k0 += 16) {
        float4 av = make_float4(0.f, 0.f, 0.f, 0.f);
        if (m0 + lm < M) av = *(const float4*)&A[(size_t)(m0 + lm) * K + k0 + lk];
        float4 wv = *(const float4*)&W[(size_t)(k0 + wr) * N2 + n0 + wc];
        float4 wg = *(const float4*)&W[(size_t)(k0 + wr) * N2 + n0 + wc + FF_];
        As[lk + 0][lm] = av.x; As[lk + 1][lm] = av.y;
        As[lk + 2][lm] = av.z; As[lk + 3][lm] = av.w;
        *(float4*)&Wv[wr][wc] = wv;
        *(float4*)&Wg[wr][wc] = wg;
        __syncthreads();
#pragma unroll
        for (int kk = 0; kk < 16; kk++) {
            float4 a  = *(const float4*)&As[kk][ty * 4];
            float4 bv = *(const float4*)&Wv[kk][tx * 4];
            float4 bg = *(const float4*)&Wg[kk][tx * 4];
            float ar[4]  = { a.x, a.y, a.z, a.w };
            float bvr[4] = { bv.x, bv.y, bv.z, bv.w };
            float bgr[4] = { bg.x, bg.y, bg.z, bg.w };
#pragma unroll
            for (int i = 0; i < 4; i++)
#pragma unroll
                for (int j = 0; j < 4; j++) {
                    accv[i][j] = fmaf(ar[i], bvr[j], accv[i][j]);
                    accg[i][j] = fmaf(ar[i], bgr[j], accg[i][j]);
                }
        }
        __syncthreads();
    }
#pragma unroll
    for (int i = 0; i < 4; i++) {
        int row = m0 + ty * 4 + i;
        if (row >= M) continue;
#pragma unroll
        for (int j = 0; j < 4; j++) {
            int col = n0 + tx * 4 + j;
            float vv = accv[i][j] + bias[col];
            float gg = accg[i][j] + bias[col + FF_];
            float gelu = 0.5f * gg * (1.f + erff(gg * 0.70710678118654752f));
            out[(size_t)row * FF_ + col] = vv * gelu;
        }
    }
}

// ---------- V transpose: v[b][tok][h*64+d] (bf16) -> vT[(b*16+h)*64+d][tok] (bf16) ----------
// Pads tokens [ntok, grid.y*64) with zeros (needed for masked cross-attn PV).
__global__ __launch_bounds__(256) void vtrans_k(const unsigned short* __restrict__ v,
                                                unsigned short* __restrict__ vT,
                                                int ntok, int tokrows, int npad) {
    __shared__ unsigned short tile[64][68];
    const int bh = blockIdx.x, b = bh >> 4, h = bh & 15;
    const int t0 = blockIdx.y * 64;
    const int tt = threadIdx.x >> 4;
    const int dg = (threadIdx.x & 15) * 4;
#pragma unroll
    for (int p = 0; p < 4; p++) {
        int tok = t0 + tt + 16 * p;
        ushort4 val = make_ushort4(0, 0, 0, 0);
        if (tok < ntok)
            val = *(const ushort4*)&v[((size_t)(b * tokrows + tok)) * D_ + h * DH_ + dg];
        *(ushort4*)&tile[tt + 16 * p][dg] = val;
    }
    __syncthreads();
#pragma unroll
    for (int p = 0; p < 4; p++) {
        int d = tt + 16 * p;
        ushort4 w;
        w.x = tile[dg + 0][d]; w.y = tile[dg + 1][d];
        w.z = tile[dg + 2][d]; w.w = tile[dg + 3][d];
        *(ushort4*)&vT[((size_t)(bh * 64 + d)) * npad + t0 + dg] = w;
    }
}

// ---------- MFMA flash attention ----------
// qb: [B][N_][1024] bf16 (pre-scaled by 0.125), kb: [B][kv_rows][1024] bf16,
// vT: [(b*16+h)*64+d][npadv] bf16 (zero-padded past n_kv), o: [B][N_][1024] f32.
// One block = 4 independent waves; wave w handles 16 query rows. No __syncthreads.
__global__ __launch_bounds__(256) void flash_mfma_k(const unsigned short* __restrict__ qb,
                                                    const unsigned short* __restrict__ kb,
                                                    const unsigned short* __restrict__ vT,
                                                    float* __restrict__ o,
                                                    int n_kv, int kv_rows, int npadv, int ntiles) {
    __shared__ unsigned short Pls[4][16][56];   // wave-private P tiles, padded rows (112B)
    const int bh = blockIdx.x, b = bh >> 4, h = bh & 15;
    const int w = threadIdx.x >> 6;
    const int lane = threadIdx.x & 63, quad = lane >> 4, l15 = lane & 15;
    const int q0 = blockIdx.y * 64 + w * 16;

    // Q A-fragments (dims 0-31 and 32-63): lane holds Q[q0+l15][quad*8 + j (+32)]
    const size_t qoff = ((size_t)(b * N_ + q0 + l15)) * D_ + h * DH_ + quad * 8;
    const short8 qf0 = *(const short8*)&qb[qoff];
    const short8 qf1 = *(const short8*)&qb[qoff + 32];

    f32x4 O0 = {0.f, 0.f, 0.f, 0.f}, O1 = O0, O2 = O0, O3 = O0;
    f32x4 m4 = {NEG_BIG, NEG_BIG, NEG_BIG, NEG_BIG};
    f32x4 l4 = {0.f, 0.f, 0.f, 0.f};

    const unsigned short* vbase = vT + (size_t)(bh * 64) * npadv;

    for (int t = 0; t < ntiles; ++t) {
        const int j0 = t * 32;
        // K B-fragments: lane holds K[j0+16s+l15][32c + quad*8 + j]
        const size_t kr0 = ((size_t)(b * kv_rows + j0 + l15)) * D_ + h * DH_ + quad * 8;
        const size_t kr1 = kr0 + (size_t)16 * D_;
        const short8 kf00 = *(const short8*)&kb[kr0];
        const short8 kf01 = *(const short8*)&kb[kr0 + 32];
        const short8 kf10 = *(const short8*)&kb[kr1];
        const short8 kf11 = *(const short8*)&kb[kr1 + 32];
        // V B-fragments (from vT): lane holds V[j0+quad*8+j][16n + l15]
        const int vcol = j0 + quad * 8;
        const short8 vf0 = *(const short8*)&vbase[(size_t)(l15     ) * npadv + vcol];
        const short8 vf1 = *(const short8*)&vbase[(size_t)(l15 + 16) * npadv + vcol];
        const short8 vf2 = *(const short8*)&vbase[(size_t)(l15 + 32) * npadv + vcol];
        const short8 vf3 = *(const short8*)&vbase[(size_t)(l15 + 48) * npadv + vcol];

        // S = Q K^T (C layout: row = quad*4+r, col = l15 (+16 for s1))
        f32x4 s0 = {0.f, 0.f, 0.f, 0.f}, s1 = s0;
        s0 = MFMA16(qf0, kf00, s0);
        s0 = MFMA16(qf1, kf01, s0);
        s1 = MFMA16(qf0, kf10, s1);
        s1 = MFMA16(qf1, kf11, s1);

        // mask invalid keys (cross-attn tail); NaN-proof (overwrites any garbage)
        if (j0 + l15 >= n_kv) { s0[0] = NEG_BIG; s0[1] = NEG_BIG; s0[2] = NEG_BIG; s0[3] = NEG_BIG; }
        if (j0 + 16 + l15 >= n_kv) { s1[0] = NEG_BIG; s1[1] = NEG_BIG; s1[2] = NEG_BIG; s1[3] = NEG_BIG; }

        // online softmax (row stats live in the 16 lanes of each quad)
        f32x4 t4;
#pragma unroll
        for (int r = 0; r < 4; r++) t4[r] = fmaxf(s0[r], s1[r]);
#pragma unroll
        for (int off = 1; off < 16; off <<= 1) {
#pragma unroll
            for (int r = 0; r < 4; r++) t4[r] = fmaxf(t4[r], __shfl_xor(t4[r], off));
        }
        f32x4 mn, al, p0, p1, u;
#pragma unroll
        for (int r = 0; r < 4; r++) {
            mn[r] = fmaxf(m4[r], t4[r]);
            al[r] = __expf(m4[r] - mn[r]);
            p0[r] = __expf(s0[r] - mn[r]);
            p1[r] = __expf(s1[r] - mn[r]);
            u[r]  = p0[r] + p1[r];
        }
#pragma unroll
        for (int off = 1; off < 16; off <<= 1) {
#pragma unroll
            for (int r = 0; r < 4; r++) u[r] += __shfl_xor(u[r], off);
        }
#pragma unroll
        for (int r = 0; r < 4; r++) {
            l4[r] = l4[r] * al[r] + u[r];
            m4[r] = mn[r];
            O0[r] *= al[r]; O1[r] *= al[r]; O2[r] *= al[r]; O3[r] *= al[r];
        }

        // P: C layout -> A layout via wave-private LDS round-trip (no barrier needed)
#pragma unroll
        for (int r = 0; r < 4; r++) {
            Pls[w][quad * 4 + r][l15]      = f2bf_raw(p0[r]);
            Pls[w][quad * 4 + r][l15 + 16] = f2bf_raw(p1[r]);
        }
        const short8 pf = *(const short8*)&Pls[w][l15][quad * 8];

        // O += P V
        O0 = MFMA16(pf, vf0, O0);
        O1 = MFMA16(pf, vf1, O1);
        O2 = MFMA16(pf, vf2, O2);
        O3 = MFMA16(pf, vf3, O3);
    }

    // epilogue: divide by l, write f32 o (C layout rows)
    const size_t obase = ((size_t)(b * N_ + q0 + quad * 4)) * D_ + h * DH_ + l15;
#pragma unroll
    for (int r = 0; r < 4; r++) {
        float inv = 1.0f / l4[r];
        float* orow = &o[obase + (size_t)r * D_];
        orow[0]  = O0[r] * inv;
        orow[16] = O1[r] * inv;
        orow[32] = O2[r] * inv;
        orow[48] = O3[r] * inv;
    }
}

// ---------- host ----------
extern "C" void kernel_launch(void* const* d_in, const int* in_sizes, int n_in,
                              void* d_out, int out_size, void* d_ws, size_t ws_size,
                              hipStream_t stream) {
    const float* x_in  = (const float*)d_in[0];
    const float* ctx_in= (const float*)d_in[1];
    const float* w1q = (const float*)d_in[2];
    const float* w1k = (const float*)d_in[3];
    const float* w1v = (const float*)d_in[4];
    const float* w1o = (const float*)d_in[5];
    const float* b1o = (const float*)d_in[6];
    const float* w2q = (const float*)d_in[7];
    const float* w2k = (const float*)d_in[8];
    const float* w2v = (const float*)d_in[9];
    const float* w2o = (const float*)d_in[10];
    const float* b2o = (const float*)d_in[11];
    const float* ln1g= (const float*)d_in[12];
    const float* ln1b= (const float*)d_in[13];
    const float* ln2g= (const float*)d_in[14];
    const float* ln2b= (const float*)d_in[15];
    const float* ln3g= (const float*)d_in[16];
    const float* ln3b= (const float*)d_in[17];
    const float* ffw1= (const float*)d_in[18];
    const float* ffb1= (const float*)d_in[19];
    const float* ffw2= (const float*)d_in[20];
    const float* ffb2= (const float*)d_in[21];
    float* out_f = (float*)d_out;

    // ws arena (96 MB):
    // xbuf f32 [0,16M) | h f32 [16,32M) | qb bf16 [32,40M) | kb bf16 [40,48M)
    // vb bf16 [48,56M) | vTb bf16 [56,64M) | ob f32 [64,80M)
    // g f32 [32,96M) overlaps qb..ob (dead during FF phase)
    char* ws = (char*)d_ws;
    float* xbuf = (float*)(ws);
    float* h    = (float*)(ws + (size_t)(16 << 20));
    unsigned short* qb  = (unsigned short*)(ws + (size_t)(32 << 20));
    unsigned short* kb  = (unsigned short*)(ws + (size_t)(40 << 20));
    unsigned short* vb  = (unsigned short*)(ws + (size_t)(48 << 20));
    unsigned short* vTb = (unsigned short*)(ws + (size_t)(56 << 20));
    float* ob   = (float*)(ws + (size_t)(64 << 20));
    float* g    = (float*)(ws + (size_t)(32 << 20));   // FF-phase overlap

    const int MT = B_ * N_;        // 4096 token rows
    const int MC = B_ * NC_;       // 154 context rows

    auto gemm_f = [&](const float* A, const float* W, const float* bias,
                      const float* res, float* outf, int M, int N, int K) {
        dim3 grid(N / 64, (M + 63) / 64);
        hipLaunchKernelGGL(gemm_k, grid, dim3(256), 0, stream,
                           A, W, bias, res, outf, (unsigned short*)nullptr, 1.0f, M, N, K);
    };
    auto gemm_b = [&](const float* A, const float* W, unsigned short* outb,
                      float scale, int M, int N, int K) {
        dim3 grid(N / 64, (M + 63) / 64);
        hipLaunchKernelGGL(gemm_k, grid, dim3(256), 0, stream,
                           A, W, (const float*)nullptr, (const float*)nullptr,
                           (float*)nullptr, outb, scale, M, N, K);
    };

    // ---- self attention ----
    hipLaunchKernelGGL(ln_k, dim3(MT), dim3(256), 0, stream, x_in, ln1g, ln1b, h);
    gemm_b(h, w1q, qb, SCALE_, MT, D_, D_);     // Q pre-scaled by 1/8 (exact in bf16)
    gemm_b(h, w1k, kb, 1.0f,   MT, D_, D_);
    gemm_b(h, w1v, vb, 1.0f,   MT, D_, D_);
    hipLaunchKernelGGL(vtrans_k, dim3(B_ * H_, N_ / 64), dim3(256), 0, stream,
                       vb, vTb, N_, N_, N_);
    hipLaunchKernelGGL(flash_mfma_k, dim3(B_ * H_, N_ / 64), dim3(256), 0, stream,
                       qb, kb, vTb, ob, N_, N_, N_, N_ / 32);
    gemm_f(ob, w1o, b1o, x_in, xbuf, MT, D_, D_);   // x = attn_out + x_in

    // ---- cross attention (n_kv = 77, padded to 96 keys / 128 vT tokens) ----
    hipLaunchKernelGGL(ln_k, dim3(MT), dim3(256), 0, stream, xbuf, ln2g, ln2b, h);
    gemm_b(h, w2q, qb, SCALE_, MT, D_, D_);
    gemm_b(ctx_in, w2k, kb, 1.0f, MC, D_, DC_);
    gemm_b(ctx_in, w2v, vb, 1.0f, MC, D_, DC_);
    hipLaunchKernelGGL(vtrans_k, dim3(B_ * H_, 2), dim3(256), 0, stream,
                       vb, vTb, NC_, NC_, 128);
    hipLaunchKernelGGL(flash_mfma_k, dim3(B_ * H_, N_ / 64), dim3(256), 0, stream,
                       qb, kb, vTb, ob, NC_, NC_, 128, 3);
    gemm_f(ob, w2o, b2o, xbuf, xbuf, MT, D_, D_);

    // ---- feed-forward (GEGLU) ----
    hipLaunchKernelGGL(ln_k, dim3(MT), dim3(256), 0, stream, xbuf, ln3g, ln3b, h);
    hipLaunchKernelGGL(geglu_k, dim3(FF_ / 64, MT / 64), dim3(256), 0, stream,
                       h, ffw1, ffb1, g, MT, D_);
    gemm_f(g, ffw2, ffb2, xbuf, out_f, MT, D_, FF_);
}

// Round 6
// 982.575 us; speedup vs baseline: 5.3736x; 2.6187x over previous
//
#include <hip/hip_runtime.h>
#include <hip/hip_bf16.h>
#include <math.h>

// Problem constants
#define B_    2
#define N_    2048
#define D_    1024
#define NC_   77
#define DC_   768
#define H_    16
#define DH_   64
#define FF_   4096
#define EPS_  1e-5f
#define SCALE_ 0.125f   // DH^-0.5
#define NEG_BIG -1e30f

typedef __attribute__((ext_vector_type(8))) short short8;   // 8 bf16 in 4 VGPRs
typedef __attribute__((ext_vector_type(4))) float f32x4;
#define MFMA16(a, b, c) __builtin_amdgcn_mfma_f32_16x16x32_bf16(a, b, c, 0, 0, 0)

// ---------- helpers ----------
static __device__ __forceinline__ unsigned short f2bf_raw(float f) {
    union { float f; unsigned int i; } x; x.f = f;
    unsigned int r = x.i + 0x7fffu + ((x.i >> 16) & 1u);   // RNE
    return (unsigned short)(r >> 16);
}

// async global->LDS, 16B per lane; LDS dest = wave-uniform base + lane*16
static __device__ __forceinline__ void gload16(const void* g, void* l) {
    __builtin_amdgcn_global_load_lds(
        (const __attribute__((address_space(1))) void*)g,
        (__attribute__((address_space(3))) void*)l, 16, 0, 0);
}

// ---------- weight transpose: src f32 [K][N] -> dst bf16 [N][K] ----------
__global__ __launch_bounds__(256) void wtrans_k(const float* __restrict__ src,
                                                unsigned short* __restrict__ dst,
                                                int K, int N) {
    __shared__ unsigned short t[64][68];
    const int k0 = blockIdx.y * 64, n0 = blockIdx.x * 64;
    const int rr = threadIdx.x >> 4;
    const int cc = (threadIdx.x & 15) * 4;
#pragma unroll
    for (int p = 0; p < 4; p++) {
        int k = rr + p * 16;
        float4 vd = *(const float4*)&src[(size_t)(k0 + k) * N + n0 + cc];
        t[k][cc + 0] = f2bf_raw(vd.x); t[k][cc + 1] = f2bf_raw(vd.y);
        t[k][cc + 2] = f2bf_raw(vd.z); t[k][cc + 3] = f2bf_raw(vd.w);
    }
    __syncthreads();
#pragma unroll
    for (int p = 0; p < 4; p++) {
        int n = rr + p * 16;
        ushort4 o;
        o.x = t[cc + 0][n]; o.y = t[cc + 1][n];
        o.z = t[cc + 2][n]; o.w = t[cc + 3][n];
        *(ushort4*)&dst[(size_t)(n0 + n) * K + k0 + cc] = o;
    }
}

// ---------- LayerNorm over D=1024, bf16 out ----------
__global__ __launch_bounds__(256) void ln_k(const float* __restrict__ x,
                                            const float* __restrict__ g,
                                            const float* __restrict__ b,
                                            unsigned short* __restrict__ out) {
    int row = blockIdx.x;
    const float* xr = x + (size_t)row * D_;
    float v0[4]; float s = 0.f, sq = 0.f;
#pragma unroll
    for (int i = 0; i < 4; i++) {
        float t = xr[threadIdx.x + 256 * i];
        v0[i] = t; s += t; sq += t * t;
    }
#pragma unroll
    for (int off = 32; off; off >>= 1) {
        s  += __shfl_xor(s,  off);
        sq += __shfl_xor(sq, off);
    }
    __shared__ float rs[4], rq[4];
    int wave = threadIdx.x >> 6, lane = threadIdx.x & 63;
    if (lane == 0) { rs[wave] = s; rq[wave] = sq; }
    __syncthreads();
    s  = rs[0] + rs[1] + rs[2] + rs[3];
    sq = rq[0] + rq[1] + rq[2] + rq[3];
    float mu  = s * (1.f / D_);
    float var = sq * (1.f / D_) - mu * mu;
    float inv = rsqrtf(var + EPS_);
#pragma unroll
    for (int i = 0; i < 4; i++) {
        int c = threadIdx.x + 256 * i;
        out[(size_t)row * D_ + c] = f2bf_raw((v0[i] - mu) * inv * g[c] + b[c]);
    }
}

// ---------- MFMA GEMM: C[M,N] = A[M,K](bf16) @ BT[N,K](bf16)^T ----------
// 128x128x32 tiles, 4 waves (2x2 of 64x64), global_load_lds staging,
// XOR k-chunk swizzle. mode 0: bf16 out, col>>10 selects {oq(scaled),ok,ov}.
// mode 1: f32 out = acc + bias + res.
__global__ __launch_bounds__(256) void gemm_mfma_k(
        const unsigned short* __restrict__ A,
        const unsigned short* __restrict__ BT,
        const float* __restrict__ bias,
        const float* __restrict__ res,
        float* __restrict__ outf,
        unsigned short* __restrict__ oq,
        unsigned short* __restrict__ ok,
        unsigned short* __restrict__ ov,
        int M, int N, int K, int mode) {
    __shared__ unsigned short As[128 * 32];
    __shared__ unsigned short Bs[128 * 32];
    const int tid = threadIdx.x;
    const int w = tid >> 6, lane = tid & 63, quad = lane >> 4, l15 = lane & 15;
    const int wm = w >> 1, wn = w & 1;
    const int m0 = blockIdx.y * 128, n0 = blockIdx.x * 128;
    const int srow = lane >> 2;                       // 0..15
    const int schunk = lane & 3;
    const int kswz = (schunk ^ (srow & 3)) * 8;       // element offset in [0,32)
    const int rdsw = (quad ^ (l15 & 3)) * 8;          // fragment read swizzle

    f32x4 acc[4][4] = {};
    for (int k0 = 0; k0 < K; k0 += 32) {
#pragma unroll
        for (int i = 0; i < 2; i++) {
            int r = (w * 2 + i) * 16;
            gload16(&A[(size_t)(m0 + r + srow) * K + k0 + kswz], &As[r * 32]);
            gload16(&BT[(size_t)(n0 + r + srow) * K + k0 + kswz], &Bs[r * 32]);
        }
        __syncthreads();
        short8 af[4], bf[4];
#pragma unroll
        for (int i = 0; i < 4; i++) {
            af[i] = *(const short8*)&As[(wm * 64 + i * 16 + l15) * 32 + rdsw];
            bf[i] = *(const short8*)&Bs[(wn * 64 + i * 16 + l15) * 32 + rdsw];
        }
#pragma unroll
        for (int i = 0; i < 4; i++)
#pragma unroll
            for (int j = 0; j < 4; j++)
                acc[i][j] = MFMA16(af[i], bf[j], acc[i][j]);
        __syncthreads();
    }
    // epilogue: C row = m0+wm*64+i*16+quad*4+r, col = n0+wn*64+j*16+l15
#pragma unroll
    for (int i = 0; i < 4; i++) {
#pragma unroll
        for (int r = 0; r < 4; r++) {
            const int row = m0 + wm * 64 + i * 16 + quad * 4 + r;
#pragma unroll
            for (int j = 0; j < 4; j++) {
                const int col = n0 + wn * 64 + j * 16 + l15;
                float c = acc[i][j][r];
                if (mode == 0) {
                    int which = col >> 10, cc = col & 1023;
                    unsigned short* dst = which == 0 ? oq : (which == 1 ? ok : ov);
                    dst[(size_t)row * 1024 + cc] = f2bf_raw(which == 0 ? c * SCALE_ : c);
                } else {
                    outf[(size_t)row * N + col] =
                        c + bias[col] + res[(size_t)row * N + col];
                }
            }
        }
    }
}

// ---------- MFMA GEGLU: g[M,4096] = (A@W[:,:FF]+bv) * gelu(A@W[:,FF:]+bg) ----------
// BT = ffw1T [8192][1024]; val rows n0.., gate rows 4096+n0..
__global__ __launch_bounds__(256) void geglu_mfma_k(
        const unsigned short* __restrict__ A,
        const unsigned short* __restrict__ BT,
        const float* __restrict__ bias,
        unsigned short* __restrict__ outg,
        int M, int K) {
    __shared__ unsigned short As[128 * 32];
    __shared__ unsigned short Bv[128 * 32];
    __shared__ unsigned short Bg[128 * 32];
    const int tid = threadIdx.x;
    const int w = tid >> 6, lane = tid & 63, quad = lane >> 4, l15 = lane & 15;
    const int wm = w >> 1, wn = w & 1;
    const int m0 = blockIdx.y * 128, n0 = blockIdx.x * 128;
    const int srow = lane >> 2;
    const int schunk = lane & 3;
    const int kswz = (schunk ^ (srow & 3)) * 8;
    const int rdsw = (quad ^ (l15 & 3)) * 8;

    f32x4 accv[4][4] = {}, accg[4][4] = {};
    for (int k0 = 0; k0 < K; k0 += 32) {
#pragma unroll
        for (int i = 0; i < 2; i++) {
            int r = (w * 2 + i) * 16;
            gload16(&A[(size_t)(m0 + r + srow) * K + k0 + kswz], &As[r * 32]);
            gload16(&BT[(size_t)(n0 + r + srow) * K + k0 + kswz], &Bv[r * 32]);
            gload16(&BT[(size_t)(FF_ + n0 + r + srow) * K + k0 + kswz], &Bg[r * 32]);
        }
        __syncthreads();
        short8 af[4], bvf[4], bgf[4];
#pragma unroll
        for (int i = 0; i < 4; i++) {
            af[i]  = *(const short8*)&As[(wm * 64 + i * 16 + l15) * 32 + rdsw];
            bvf[i] = *(const short8*)&Bv[(wn * 64 + i * 16 + l15) * 32 + rdsw];
            bgf[i] = *(const short8*)&Bg[(wn * 64 + i * 16 + l15) * 32 + rdsw];
        }
#pragma unroll
        for (int i = 0; i < 4; i++)
#pragma unroll
            for (int j = 0; j < 4; j++) {
                accv[i][j] = MFMA16(af[i], bvf[j], accv[i][j]);
                accg[i][j] = MFMA16(af[i], bgf[j], accg[i][j]);
            }
        __syncthreads();
    }
#pragma unroll
    for (int i = 0; i < 4; i++) {
#pragma unroll
        for (int r = 0; r < 4; r++) {
            const int row = m0 + wm * 64 + i * 16 + quad * 4 + r;
#pragma unroll
            for (int j = 0; j < 4; j++) {
                const int col = n0 + wn * 64 + j * 16 + l15;
                float vv = accv[i][j][r] + bias[col];
                float gg = accg[i][j][r] + bias[col + FF_];
                float ge = 0.5f * gg * (1.f + erff(gg * 0.70710678118654752f));
                outg[(size_t)row * FF_ + col] = f2bf_raw(vv * ge);
            }
        }
    }
}

// ---------- old f32 GEMM (kept for tiny ctx K/V: M=154) ----------
__global__ __launch_bounds__(256) void gemm_k(const float* __restrict__ A,
                                              const float* __restrict__ W,
                                              unsigned short* __restrict__ outb,
                                              int M, int N, int K) {
    __shared__ float As[16][64];
    __shared__ float Ws[16][64];
    const int tx = threadIdx.x & 15;
    const int ty = threadIdx.x >> 4;
    const int m0 = blockIdx.y * 64, n0 = blockIdx.x * 64;
    const int lm = threadIdx.x >> 2;
    const int lk = (threadIdx.x & 3) * 4;
    const int wr = threadIdx.x >> 4;
    const int wc = (threadIdx.x & 15) * 4;
    float acc[4][4] = {};
    for (int k0 = 0; k0 < K; k0 += 16) {
        float4 av = make_float4(0.f, 0.f, 0.f, 0.f);
        if (m0 + lm < M) av = *(const float4*)&A[(size_t)(m0 + lm) * K + k0 + lk];
        float4 wv = *(const float4*)&W[(size_t)(k0 + wr) * N + n0 + wc];
        As[lk + 0][lm] = av.x; As[lk + 1][lm] = av.y;
        As[lk + 2][lm] = av.z; As[lk + 3][lm] = av.w;
        *(float4*)&Ws[wr][wc] = wv;
        __syncthreads();
#pragma unroll
        for (int kk = 0; kk < 16; kk++) {
            float4 a = *(const float4*)&As[kk][ty * 4];
            float4 b = *(const float4*)&Ws[kk][tx * 4];
            float ar[4] = { a.x, a.y, a.z, a.w };
            float br[4] = { b.x, b.y, b.z, b.w };
#pragma unroll
            for (int i = 0; i < 4; i++)
#pragma unroll
                for (int j = 0; j < 4; j++)
                    acc[i][j] = fmaf(ar[i], br[j], acc[i][j]);
        }
        __syncthreads();
    }
#pragma unroll
    for (int i = 0; i < 4; i++) {
        int row = m0 + ty * 4 + i;
        if (row >= M) continue;
        ushort4 u;
        u.x = f2bf_raw(acc[i][0]); u.y = f2bf_raw(acc[i][1]);
        u.z = f2bf_raw(acc[i][2]); u.w = f2bf_raw(acc[i][3]);
        *(ushort4*)&outb[(size_t)row * N + n0 + tx * 4] = u;
    }
}

// ---------- V transpose: v[b][tok][h*64+d] -> vT[(b*16+h)*64+d][tok] (bf16) ----------
__global__ __launch_bounds__(256) void vtrans_k(const unsigned short* __restrict__ v,
                                                unsigned short* __restrict__ vT,
                                                int ntok, int tokrows, int npad) {
    __shared__ unsigned short tile[64][68];
    const int bh = blockIdx.x, b = bh >> 4, h = bh & 15;
    const int t0 = blockIdx.y * 64;
    const int tt = threadIdx.x >> 4;
    const int dg = (threadIdx.x & 15) * 4;
#pragma unroll
    for (int p = 0; p < 4; p++) {
        int tok = t0 + tt + 16 * p;
        ushort4 val = make_ushort4(0, 0, 0, 0);
        if (tok < ntok)
            val = *(const ushort4*)&v[((size_t)(b * tokrows + tok)) * D_ + h * DH_ + dg];
        *(ushort4*)&tile[tt + 16 * p][dg] = val;
    }
    __syncthreads();
#pragma unroll
    for (int p = 0; p < 4; p++) {
        int d = tt + 16 * p;
        ushort4 w;
        w.x = tile[dg + 0][d]; w.y = tile[dg + 1][d];
        w.z = tile[dg + 2][d]; w.w = tile[dg + 3][d];
        *(ushort4*)&vT[((size_t)(bh * 64 + d)) * npad + t0 + dg] = w;
    }
}

// ---------- MFMA flash attention (bf16 in, bf16 out) ----------
__global__ __launch_bounds__(256) void flash_mfma_k(const unsigned short* __restrict__ qb,
                                                    const unsigned short* __restrict__ kb,
                                                    const unsigned short* __restrict__ vT,
                                                    unsigned short* __restrict__ o,
                                                    int n_kv, int kv_rows, int npadv, int ntiles) {
    __shared__ unsigned short Pls[4][16][56];
    const int bh = blockIdx.x, b = bh >> 4, h = bh & 15;
    const int w = threadIdx.x >> 6;
    const int lane = threadIdx.x & 63, quad = lane >> 4, l15 = lane & 15;
    const int q0 = blockIdx.y * 64 + w * 16;

    const size_t qoff = ((size_t)(b * N_ + q0 + l15)) * D_ + h * DH_ + quad * 8;
    const short8 qf0 = *(const short8*)&qb[qoff];
    const short8 qf1 = *(const short8*)&qb[qoff + 32];

    f32x4 O0 = {0.f, 0.f, 0.f, 0.f}, O1 = O0, O2 = O0, O3 = O0;
    f32x4 m4 = {NEG_BIG, NEG_BIG, NEG_BIG, NEG_BIG};
    f32x4 l4 = {0.f, 0.f, 0.f, 0.f};

    const unsigned short* vbase = vT + (size_t)(bh * 64) * npadv;

    for (int t = 0; t < ntiles; ++t) {
        const int j0 = t * 32;
        const size_t kr0 = ((size_t)(b * kv_rows + j0 + l15)) * D_ + h * DH_ + quad * 8;
        const size_t kr1 = kr0 + (size_t)16 * D_;
        const short8 kf00 = *(const short8*)&kb[kr0];
        const short8 kf01 = *(const short8*)&kb[kr0 + 32];
        const short8 kf10 = *(const short8*)&kb[kr1];
        const short8 kf11 = *(const short8*)&kb[kr1 + 32];
        const int vcol = j0 + quad * 8;
        const short8 vf0 = *(const short8*)&vbase[(size_t)(l15     ) * npadv + vcol];
        const short8 vf1 = *(const short8*)&vbase[(size_t)(l15 + 16) * npadv + vcol];
        const short8 vf2 = *(const short8*)&vbase[(size_t)(l15 + 32) * npadv + vcol];
        const short8 vf3 = *(const short8*)&vbase[(size_t)(l15 + 48) * npadv + vcol];

        f32x4 s0 = {0.f, 0.f, 0.f, 0.f}, s1 = s0;
        s0 = MFMA16(qf0, kf00, s0);
        s0 = MFMA16(qf1, kf01, s0);
        s1 = MFMA16(qf0, kf10, s1);
        s1 = MFMA16(qf1, kf11, s1);

        if (j0 + l15 >= n_kv) { s0[0] = NEG_BIG; s0[1] = NEG_BIG; s0[2] = NEG_BIG; s0[3] = NEG_BIG; }
        if (j0 + 16 + l15 >= n_kv) { s1[0] = NEG_BIG; s1[1] = NEG_BIG; s1[2] = NEG_BIG; s1[3] = NEG_BIG; }

        f32x4 t4;
#pragma unroll
        for (int r = 0; r < 4; r++) t4[r] = fmaxf(s0[r], s1[r]);
#pragma unroll
        for (int off = 1; off < 16; off <<= 1) {
#pragma unroll
            for (int r = 0; r < 4; r++) t4[r] = fmaxf(t4[r], __shfl_xor(t4[r], off));
        }
        f32x4 mn, al, p0, p1, u;
#pragma unroll
        for (int r = 0; r < 4; r++) {
            mn[r] = fmaxf(m4[r], t4[r]);
            al[r] = __expf(m4[r] - mn[r]);
            p0[r] = __expf(s0[r] - mn[r]);
            p1[r] = __expf(s1[r] - mn[r]);
            u[r]  = p0[r] + p1[r];
        }
#pragma unroll
        for (int off = 1; off < 16; off <<= 1) {
#pragma unroll
            for (int r = 0; r < 4; r++) u[r] += __shfl_xor(u[r], off);
        }
#pragma unroll
        for (int r = 0; r < 4; r++) {
            l4[r] = l4[r] * al[r] + u[r];
            m4[r] = mn[r];
            O0[r] *= al[r]; O1[r] *= al[r]; O2[r] *= al[r]; O3[r] *= al[r];
        }
#pragma unroll
        for (int r = 0; r < 4; r++) {
            Pls[w][quad * 4 + r][l15]      = f2bf_raw(p0[r]);
            Pls[w][quad * 4 + r][l15 + 16] = f2bf_raw(p1[r]);
        }
        const short8 pf = *(const short8*)&Pls[w][l15][quad * 8];

        O0 = MFMA16(pf, vf0, O0);
        O1 = MFMA16(pf, vf1, O1);
        O2 = MFMA16(pf, vf2, O2);
        O3 = MFMA16(pf, vf3, O3);
    }

    const size_t obase = ((size_t)(b * N_ + q0 + quad * 4)) * D_ + h * DH_ + l15;
#pragma unroll
    for (int r = 0; r < 4; r++) {
        float inv = 1.0f / l4[r];
        unsigned short* orow = &o[obase + (size_t)r * D_];
        orow[0]  = f2bf_raw(O0[r] * inv);
        orow[16] = f2bf_raw(O1[r] * inv);
        orow[32] = f2bf_raw(O2[r] * inv);
        orow[48] = f2bf_raw(O3[r] * inv);
    }
}

// ---------- host ----------
extern "C" void kernel_launch(void* const* d_in, const int* in_sizes, int n_in,
                              void* d_out, int out_size, void* d_ws, size_t ws_size,
                              hipStream_t stream) {
    const float* x_in  = (const float*)d_in[0];
    const float* ctx_in= (const float*)d_in[1];
    const float* w1q = (const float*)d_in[2];
    const float* w1k = (const float*)d_in[3];
    const float* w1v = (const float*)d_in[4];
    const float* w1o = (const float*)d_in[5];
    const float* b1o = (const float*)d_in[6];
    const float* w2q = (const float*)d_in[7];
    const float* w2k = (const float*)d_in[8];
    const float* w2v = (const float*)d_in[9];
    const float* w2o = (const float*)d_in[10];
    const float* b2o = (const float*)d_in[11];
    const float* ln1g= (const float*)d_in[12];
    const float* ln1b= (const float*)d_in[13];
    const float* ln2g= (const float*)d_in[14];
    const float* ln2b= (const float*)d_in[15];
    const float* ln3g= (const float*)d_in[16];
    const float* ln3b= (const float*)d_in[17];
    const float* ffw1= (const float*)d_in[18];
    const float* ffb1= (const float*)d_in[19];
    const float* ffw2= (const float*)d_in[20];
    const float* ffb2= (const float*)d_in[21];
    float* out_f = (float*)d_out;

    // ws arena (92 MB total):
    // wT: wqkvT[3072][1024]@0 (6M) | w1oT@6M (2M) | w2qT@8M (2M) | w2oT@10M (2M)
    //     ffw1T[8192][1024]@12M (16M) | ffw2T[1024][4096]@28M (8M)   -> 36M
    // xbuf f32 @36M (16M) | h bf16 @52M (8M)
    // R @60M: qb@60M kb@68M vTb@76M vb/ob@84M (8M each) -> 92M
    // g bf16 [4096][4096] @60M (32M) overlaps R (dead during FF)
    char* ws = (char*)d_ws;
    unsigned short* wqkvT = (unsigned short*)(ws);
    unsigned short* w1oT  = (unsigned short*)(ws + (size_t)( 6 << 20));
    unsigned short* w2qT  = (unsigned short*)(ws + (size_t)( 8 << 20));
    unsigned short* w2oT  = (unsigned short*)(ws + (size_t)(10 << 20));
    unsigned short* ffw1T = (unsigned short*)(ws + (size_t)(12 << 20));
    unsigned short* ffw2T = (unsigned short*)(ws + (size_t)(28 << 20));
    float*          xbuf  = (float*)         (ws + (size_t)(36 << 20));
    unsigned short* h     = (unsigned short*)(ws + (size_t)(52 << 20));
    unsigned short* qb    = (unsigned short*)(ws + (size_t)(60 << 20));
    unsigned short* kb    = (unsigned short*)(ws + (size_t)(68 << 20));
    unsigned short* vTb   = (unsigned short*)(ws + (size_t)(76 << 20));
    unsigned short* vb    = (unsigned short*)(ws + (size_t)(84 << 20));  // = ob
    unsigned short* g     = (unsigned short*)(ws + (size_t)(60 << 20));

    const int MT = B_ * N_;        // 4096 token rows

    auto wt = [&](const float* src, unsigned short* dst, int K, int N) {
        hipLaunchKernelGGL(wtrans_k, dim3(N / 64, K / 64), dim3(256), 0, stream, src, dst, K, N);
    };
    auto gmm = [&](const unsigned short* A, const unsigned short* BT,
                   const float* bias, const float* res, float* outf,
                   unsigned short* oq, unsigned short* ok, unsigned short* ov,
                   int M, int N, int K, int mode) {
        hipLaunchKernelGGL(gemm_mfma_k, dim3(N / 128, M / 128), dim3(256), 0, stream,
                           A, BT, bias, res, outf, oq, ok, ov, M, N, K, mode);
    };

    // weight transposes (bf16, W^T layout)
    wt(w1q, wqkvT,                 D_, D_);
    wt(w1k, wqkvT + (1024 * 1024), D_, D_);
    wt(w1v, wqkvT + (2048 * 1024), D_, D_);
    wt(w1o, w1oT, D_, D_);
    wt(w2q, w2qT, D_, D_);
    wt(w2o, w2oT, D_, D_);
    wt(ffw1, ffw1T, D_, 2 * FF_);
    wt(ffw2, ffw2T, FF_, D_);

    // ---- self attention ----
    hipLaunchKernelGGL(ln_k, dim3(MT), dim3(256), 0, stream, x_in, ln1g, ln1b, h);
    gmm(h, wqkvT, nullptr, nullptr, nullptr, qb, kb, vb, MT, 3072, D_, 0);
    hipLaunchKernelGGL(vtrans_k, dim3(B_ * H_, N_ / 64), dim3(256), 0, stream,
                       vb, vTb, N_, N_, N_);
    hipLaunchKernelGGL(flash_mfma_k, dim3(B_ * H_, N_ / 64), dim3(256), 0, stream,
                       qb, kb, vTb, vb /*=ob*/, N_, N_, N_, N_ / 32);
    gmm(vb /*=ob*/, w1oT, b1o, x_in, xbuf, nullptr, nullptr, nullptr, MT, D_, D_, 1);

    // ---- cross attention ----
    hipLaunchKernelGGL(ln_k, dim3(MT), dim3(256), 0, stream, xbuf, ln2g, ln2b, h);
    gmm(h, w2qT, nullptr, nullptr, nullptr, qb, qb, qb, MT, D_, D_, 0);
    hipLaunchKernelGGL(gemm_k, dim3(D_ / 64, 3), dim3(256), 0, stream,
                       ctx_in, w2k, kb, B_ * NC_, D_, DC_);
    hipLaunchKernelGGL(gemm_k, dim3(D_ / 64, 3), dim3(256), 0, stream,
                       ctx_in, w2v, vb, B_ * NC_, D_, DC_);
    hipLaunchKernelGGL(vtrans_k, dim3(B_ * H_, 2), dim3(256), 0, stream,
                       vb, vTb, NC_, NC_, 128);
    hipLaunchKernelGGL(flash_mfma_k, dim3(B_ * H_, N_ / 64), dim3(256), 0, stream,
                       qb, kb, vTb, vb /*=ob*/, NC_, NC_, 128, 3);
    gmm(vb /*=ob*/, w2oT, b2o, xbuf, xbuf, nullptr, nullptr, nullptr, MT, D_, D_, 1);

    // ---- feed-forward (GEGLU) ----
    hipLaunchKernelGGL(ln_k, dim3(MT), dim3(256), 0, stream, xbuf, ln3g, ln3b, h);
    hipLaunchKernelGGL(geglu_mfma_k, dim3(FF_ / 128, MT / 128), dim3(256), 0, stream,
                       h, ffw1T, ffb1, g, MT, D_);
    gmm(g, ffw2T, ffb2, xbuf, out_f, nullptr, nullptr, nullptr, MT, D_, FF_, 1);
}

// Round 7
// 982.475 us; speedup vs baseline: 5.3741x; 1.0001x over previous
//
#include <hip/hip_runtime.h>
#include <hip/hip_bf16.h>
#include <math.h>

// Problem constants
#define B_    2
#define N_    2048
#define D_    1024
#define NC_   77
#define DC_   768
#define H_    16
#define DH_   64
#define FF_   4096
#define EPS_  1e-5f
#define SCALE_ 0.125f   // DH^-0.5
#define NEG_BIG -1e30f

typedef __attribute__((ext_vector_type(8))) short short8;   // 8 bf16 in 4 VGPRs
typedef __attribute__((ext_vector_type(4))) float f32x4;
#define MFMA16(a, b, c) __builtin_amdgcn_mfma_f32_16x16x32_bf16(a, b, c, 0, 0, 0)

// ---------- helpers ----------
static __device__ __forceinline__ unsigned short f2bf_raw(float f) {
    union { float f; unsigned int i; } x; x.f = f;
    unsigned int r = x.i + 0x7fffu + ((x.i >> 16) & 1u);   // RNE
    return (unsigned short)(r >> 16);
}

// async global->LDS, 16B per lane; LDS dest = wave-uniform base + lane*16
static __device__ __forceinline__ void gload16(const void* g, void* l) {
    __builtin_amdgcn_global_load_lds(
        (const __attribute__((address_space(1))) void*)g,
        (__attribute__((address_space(3))) void*)l, 16, 0, 0);
}

// ---------- weight transpose: src f32 [K][N] -> dst bf16 [N][K] ----------
__global__ __launch_bounds__(256) void wtrans_k(const float* __restrict__ src,
                                                unsigned short* __restrict__ dst,
                                                int K, int N) {
    __shared__ unsigned short t[64][68];
    const int k0 = blockIdx.y * 64, n0 = blockIdx.x * 64;
    const int rr = threadIdx.x >> 4;
    const int cc = (threadIdx.x & 15) * 4;
#pragma unroll
    for (int p = 0; p < 4; p++) {
        int k = rr + p * 16;
        float4 vd = *(const float4*)&src[(size_t)(k0 + k) * N + n0 + cc];
        t[k][cc + 0] = f2bf_raw(vd.x); t[k][cc + 1] = f2bf_raw(vd.y);
        t[k][cc + 2] = f2bf_raw(vd.z); t[k][cc + 3] = f2bf_raw(vd.w);
    }
    __syncthreads();
#pragma unroll
    for (int p = 0; p < 4; p++) {
        int n = rr + p * 16;
        ushort4 o;
        o.x = t[cc + 0][n]; o.y = t[cc + 1][n];
        o.z = t[cc + 2][n]; o.w = t[cc + 3][n];
        *(ushort4*)&dst[(size_t)(n0 + n) * K + k0 + cc] = o;
    }
}

// ---------- LayerNorm over D=1024, bf16 out ----------
__global__ __launch_bounds__(256) void ln_k(const float* __restrict__ x,
                                            const float* __restrict__ g,
                                            const float* __restrict__ b,
                                            unsigned short* __restrict__ out) {
    int row = blockIdx.x;
    const float* xr = x + (size_t)row * D_;
    float v0[4]; float s = 0.f, sq = 0.f;
#pragma unroll
    for (int i = 0; i < 4; i++) {
        float t = xr[threadIdx.x + 256 * i];
        v0[i] = t; s += t; sq += t * t;
    }
#pragma unroll
    for (int off = 32; off; off >>= 1) {
        s  += __shfl_xor(s,  off);
        sq += __shfl_xor(sq, off);
    }
    __shared__ float rs[4], rq[4];
    int wave = threadIdx.x >> 6, lane = threadIdx.x & 63;
    if (lane == 0) { rs[wave] = s; rq[wave] = sq; }
    __syncthreads();
    s  = rs[0] + rs[1] + rs[2] + rs[3];
    sq = rq[0] + rq[1] + rq[2] + rq[3];
    float mu  = s * (1.f / D_);
    float var = sq * (1.f / D_) - mu * mu;
    float inv = rsqrtf(var + EPS_);
#pragma unroll
    for (int i = 0; i < 4; i++) {
        int c = threadIdx.x + 256 * i;
        out[(size_t)row * D_ + c] = f2bf_raw((v0[i] - mu) * inv * g[c] + b[c]);
    }
}

// ---------- MFMA GEMM: C[M,N] = A[M,K](bf16) @ BT[N,K](bf16)^T ----------
__global__ __launch_bounds__(256) void gemm_mfma_k(
        const unsigned short* __restrict__ A,
        const unsigned short* __restrict__ BT,
        const float* __restrict__ bias,
        const float* __restrict__ res,
        float* __restrict__ outf,
        unsigned short* __restrict__ oq,
        unsigned short* __restrict__ ok,
        unsigned short* __restrict__ ov,
        int M, int N, int K, int mode) {
    __shared__ unsigned short As[128 * 32];
    __shared__ unsigned short Bs[128 * 32];
    const int tid = threadIdx.x;
    const int w = tid >> 6, lane = tid & 63, quad = lane >> 4, l15 = lane & 15;
    const int wm = w >> 1, wn = w & 1;
    const int m0 = blockIdx.y * 128, n0 = blockIdx.x * 128;
    const int srow = lane >> 2;
    const int schunk = lane & 3;
    const int kswz = (schunk ^ (srow & 3)) * 8;
    const int rdsw = (quad ^ (l15 & 3)) * 8;

    f32x4 acc[4][4] = {};
    for (int k0 = 0; k0 < K; k0 += 32) {
#pragma unroll
        for (int i = 0; i < 2; i++) {
            int r = (w * 2 + i) * 16;
            gload16(&A[(size_t)(m0 + r + srow) * K + k0 + kswz], &As[r * 32]);
            gload16(&BT[(size_t)(n0 + r + srow) * K + k0 + kswz], &Bs[r * 32]);
        }
        __syncthreads();
        short8 af[4], bf[4];
#pragma unroll
        for (int i = 0; i < 4; i++) {
            af[i] = *(const short8*)&As[(wm * 64 + i * 16 + l15) * 32 + rdsw];
            bf[i] = *(const short8*)&Bs[(wn * 64 + i * 16 + l15) * 32 + rdsw];
        }
#pragma unroll
        for (int i = 0; i < 4; i++)
#pragma unroll
            for (int j = 0; j < 4; j++)
                acc[i][j] = MFMA16(af[i], bf[j], acc[i][j]);
        __syncthreads();
    }
#pragma unroll
    for (int i = 0; i < 4; i++) {
#pragma unroll
        for (int r = 0; r < 4; r++) {
            const int row = m0 + wm * 64 + i * 16 + quad * 4 + r;
#pragma unroll
            for (int j = 0; j < 4; j++) {
                const int col = n0 + wn * 64 + j * 16 + l15;
                float c = acc[i][j][r];
                if (mode == 0) {
                    int which = col >> 10, cc = col & 1023;
                    unsigned short* dst = which == 0 ? oq : (which == 1 ? ok : ov);
                    dst[(size_t)row * 1024 + cc] = f2bf_raw(which == 0 ? c * SCALE_ : c);
                } else {
                    outf[(size_t)row * N + col] =
                        c + bias[col] + res[(size_t)row * N + col];
                }
            }
        }
    }
}

// ---------- MFMA GEGLU ----------
__global__ __launch_bounds__(256) void geglu_mfma_k(
        const unsigned short* __restrict__ A,
        const unsigned short* __restrict__ BT,
        const float* __restrict__ bias,
        unsigned short* __restrict__ outg,
        int M, int K) {
    __shared__ unsigned short As[128 * 32];
    __shared__ unsigned short Bv[128 * 32];
    __shared__ unsigned short Bg[128 * 32];
    const int tid = threadIdx.x;
    const int w = tid >> 6, lane = tid & 63, quad = lane >> 4, l15 = lane & 15;
    const int wm = w >> 1, wn = w & 1;
    const int m0 = blockIdx.y * 128, n0 = blockIdx.x * 128;
    const int srow = lane >> 2;
    const int schunk = lane & 3;
    const int kswz = (schunk ^ (srow & 3)) * 8;
    const int rdsw = (quad ^ (l15 & 3)) * 8;

    f32x4 accv[4][4] = {}, accg[4][4] = {};
    for (int k0 = 0; k0 < K; k0 += 32) {
#pragma unroll
        for (int i = 0; i < 2; i++) {
            int r = (w * 2 + i) * 16;
            gload16(&A[(size_t)(m0 + r + srow) * K + k0 + kswz], &As[r * 32]);
            gload16(&BT[(size_t)(n0 + r + srow) * K + k0 + kswz], &Bv[r * 32]);
            gload16(&BT[(size_t)(FF_ + n0 + r + srow) * K + k0 + kswz], &Bg[r * 32]);
        }
        __syncthreads();
        short8 af[4], bvf[4], bgf[4];
#pragma unroll
        for (int i = 0; i < 4; i++) {
            af[i]  = *(const short8*)&As[(wm * 64 + i * 16 + l15) * 32 + rdsw];
            bvf[i] = *(const short8*)&Bv[(wn * 64 + i * 16 + l15) * 32 + rdsw];
            bgf[i] = *(const short8*)&Bg[(wn * 64 + i * 16 + l15) * 32 + rdsw];
        }
#pragma unroll
        for (int i = 0; i < 4; i++)
#pragma unroll
            for (int j = 0; j < 4; j++) {
                accv[i][j] = MFMA16(af[i], bvf[j], accv[i][j]);
                accg[i][j] = MFMA16(af[i], bgf[j], accg[i][j]);
            }
        __syncthreads();
    }
#pragma unroll
    for (int i = 0; i < 4; i++) {
#pragma unroll
        for (int r = 0; r < 4; r++) {
            const int row = m0 + wm * 64 + i * 16 + quad * 4 + r;
#pragma unroll
            for (int j = 0; j < 4; j++) {
                const int col = n0 + wn * 64 + j * 16 + l15;
                float vv = accv[i][j][r] + bias[col];
                float gg = accg[i][j][r] + bias[col + FF_];
                float ge = 0.5f * gg * (1.f + erff(gg * 0.70710678118654752f));
                outg[(size_t)row * FF_ + col] = f2bf_raw(vv * ge);
            }
        }
    }
}

// ---------- old f32 GEMM (tiny ctx K/V: M=154) ----------
__global__ __launch_bounds__(256) void gemm_k(const float* __restrict__ A,
                                              const float* __restrict__ W,
                                              unsigned short* __restrict__ outb,
                                              int M, int N, int K) {
    __shared__ float As[16][64];
    __shared__ float Ws[16][64];
    const int tx = threadIdx.x & 15;
    const int ty = threadIdx.x >> 4;
    const int m0 = blockIdx.y * 64, n0 = blockIdx.x * 64;
    const int lm = threadIdx.x >> 2;
    const int lk = (threadIdx.x & 3) * 4;
    const int wr = threadIdx.x >> 4;
    const int wc = (threadIdx.x & 15) * 4;
    float acc[4][4] = {};
    for (int k0 = 0; k0 < K; k0 += 16) {
        float4 av = make_float4(0.f, 0.f, 0.f, 0.f);
        if (m0 + lm < M) av = *(const float4*)&A[(size_t)(m0 + lm) * K + k0 + lk];
        float4 wv = *(const float4*)&W[(size_t)(k0 + wr) * N + n0 + wc];
        As[lk + 0][lm] = av.x; As[lk + 1][lm] = av.y;
        As[lk + 2][lm] = av.z; As[lk + 3][lm] = av.w;
        *(float4*)&Ws[wr][wc] = wv;
        __syncthreads();
#pragma unroll
        for (int kk = 0; kk < 16; kk++) {
            float4 a = *(const float4*)&As[kk][ty * 4];
            float4 b = *(const float4*)&Ws[kk][tx * 4];
            float ar[4] = { a.x, a.y, a.z, a.w };
            float br[4] = { b.x, b.y, b.z, b.w };
#pragma unroll
            for (int i = 0; i < 4; i++)
#pragma unroll
                for (int j = 0; j < 4; j++)
                    acc[i][j] = fmaf(ar[i], br[j], acc[i][j]);
        }
        __syncthreads();
    }
#pragma unroll
    for (int i = 0; i < 4; i++) {
        int row = m0 + ty * 4 + i;
        if (row >= M) continue;
        ushort4 u;
        u.x = f2bf_raw(acc[i][0]); u.y = f2bf_raw(acc[i][1]);
        u.z = f2bf_raw(acc[i][2]); u.w = f2bf_raw(acc[i][3]);
        *(ushort4*)&outb[(size_t)row * N + n0 + tx * 4] = u;
    }
}

// ---------- V transpose ----------
__global__ __launch_bounds__(256) void vtrans_k(const unsigned short* __restrict__ v,
                                                unsigned short* __restrict__ vT,
                                                int ntok, int tokrows, int npad) {
    __shared__ unsigned short tile[64][68];
    const int bh = blockIdx.x, b = bh >> 4, h = bh & 15;
    const int t0 = blockIdx.y * 64;
    const int tt = threadIdx.x >> 4;
    const int dg = (threadIdx.x & 15) * 4;
#pragma unroll
    for (int p = 0; p < 4; p++) {
        int tok = t0 + tt + 16 * p;
        ushort4 val = make_ushort4(0, 0, 0, 0);
        if (tok < ntok)
            val = *(const ushort4*)&v[((size_t)(b * tokrows + tok)) * D_ + h * DH_ + dg];
        *(ushort4*)&tile[tt + 16 * p][dg] = val;
    }
    __syncthreads();
#pragma unroll
    for (int p = 0; p < 4; p++) {
        int d = tt + 16 * p;
        ushort4 w;
        w.x = tile[dg + 0][d]; w.y = tile[dg + 1][d];
        w.z = tile[dg + 2][d]; w.w = tile[dg + 3][d];
        *(ushort4*)&vT[((size_t)(bh * 64 + d)) * npad + t0 + dg] = w;
    }
}

// ---------- MFMA flash attention v2: 64-key tiles, softmax-sum via ones-MFMA ----------
// One wave = 16 query rows. No __syncthreads. l accumulated as extra MFMA column.
__global__ __launch_bounds__(256) void flash_mfma_k(const unsigned short* __restrict__ qb,
                                                    const unsigned short* __restrict__ kb,
                                                    const unsigned short* __restrict__ vT,
                                                    unsigned short* __restrict__ o,
                                                    int n_kv, int kv_rows, int npadv, int ntiles) {
    __shared__ unsigned short Pls[4][16][72];   // row stride 144 B (16B-aligned reads)
    const int bh = blockIdx.x, b = bh >> 4, h = bh & 15;
    const int w = threadIdx.x >> 6;
    const int lane = threadIdx.x & 63, quad = lane >> 4, l15 = lane & 15;
    const int q0 = blockIdx.y * 64 + w * 16;

    const size_t qoff = ((size_t)(b * N_ + q0 + l15)) * D_ + h * DH_ + quad * 8;
    const short8 qf0 = *(const short8*)&qb[qoff];
    const short8 qf1 = *(const short8*)&qb[qoff + 32];

    short8 onesf;
#pragma unroll
    for (int i = 0; i < 8; i++) onesf[i] = (short)0x3F80;   // bf16 1.0

    f32x4 O0 = {0.f, 0.f, 0.f, 0.f}, O1 = O0, O2 = O0, O3 = O0, L4 = O0;
    f32x4 m4 = {NEG_BIG, NEG_BIG, NEG_BIG, NEG_BIG};

    const unsigned short* vbase = vT + (size_t)(bh * 64) * npadv;

    for (int t = 0; t < ntiles; ++t) {
        const int j0 = t * 64;
        // K B-fragments: key rows j0+16*cb+l15, dims quad*8 (+32)
        short8 kf[4][2];
#pragma unroll
        for (int cb = 0; cb < 4; cb++) {
            const size_t kr = ((size_t)(b * kv_rows + j0 + 16 * cb + l15)) * D_ + h * DH_ + quad * 8;
            kf[cb][0] = *(const short8*)&kb[kr];
            kf[cb][1] = *(const short8*)&kb[kr + 32];
        }
        // V B-fragments: vT rows (dims) l15+16n, key cols j0+quad*8 (+32)
        short8 vf[4][2];
#pragma unroll
        for (int n = 0; n < 4; n++) {
            const size_t vr = (size_t)(l15 + 16 * n) * npadv + j0 + quad * 8;
            vf[n][0] = *(const short8*)&vbase[vr];
            vf[n][1] = *(const short8*)&vbase[vr + 32];
        }

        // S = Q K^T for 64 keys (4 col-blocks of 16)
        f32x4 s[4];
#pragma unroll
        for (int cb = 0; cb < 4; cb++) {
            f32x4 z = {0.f, 0.f, 0.f, 0.f};
            z = MFMA16(qf0, kf[cb][0], z);
            z = MFMA16(qf1, kf[cb][1], z);
            s[cb] = z;
        }

        // mask invalid keys (cross-attn tail)
#pragma unroll
        for (int cb = 0; cb < 4; cb++)
            if (j0 + 16 * cb + l15 >= n_kv) {
                s[cb][0] = NEG_BIG; s[cb][1] = NEG_BIG;
                s[cb][2] = NEG_BIG; s[cb][3] = NEG_BIG;
            }

        // row max over 64 keys: fold col-blocks, then 16-lane shuffle reduce
        f32x4 t4;
#pragma unroll
        for (int r = 0; r < 4; r++)
            t4[r] = fmaxf(fmaxf(s[0][r], s[1][r]), fmaxf(s[2][r], s[3][r]));
#pragma unroll
        for (int off = 1; off < 16; off <<= 1) {
#pragma unroll
            for (int r = 0; r < 4; r++) t4[r] = fmaxf(t4[r], __shfl_xor(t4[r], off));
        }
        f32x4 mn, al;
#pragma unroll
        for (int r = 0; r < 4; r++) {
            mn[r] = fmaxf(m4[r], t4[r]);
            al[r] = __expf(m4[r] - mn[r]);
            m4[r] = mn[r];
        }
        // p = exp(s - mn), write to LDS in C layout
#pragma unroll
        for (int cb = 0; cb < 4; cb++) {
#pragma unroll
            for (int r = 0; r < 4; r++)
                Pls[w][quad * 4 + r][l15 + 16 * cb] = f2bf_raw(__expf(s[cb][r] - mn[r]));
        }
        // rescale accumulators (L4 included — it's just another PV column set)
#pragma unroll
        for (int r = 0; r < 4; r++) {
            O0[r] *= al[r]; O1[r] *= al[r]; O2[r] *= al[r]; O3[r] *= al[r];
            L4[r] *= al[r];
        }
        // P A-fragments (keys 0-31 and 32-63)
        const short8 pf0 = *(const short8*)&Pls[w][l15][quad * 8];
        const short8 pf1 = *(const short8*)&Pls[w][l15][32 + quad * 8];

        // O += P V ; L += P * 1
        O0 = MFMA16(pf0, vf[0][0], O0); O0 = MFMA16(pf1, vf[0][1], O0);
        O1 = MFMA16(pf0, vf[1][0], O1); O1 = MFMA16(pf1, vf[1][1], O1);
        O2 = MFMA16(pf0, vf[2][0], O2); O2 = MFMA16(pf1, vf[2][1], O2);
        O3 = MFMA16(pf0, vf[3][0], O3); O3 = MFMA16(pf1, vf[3][1], O3);
        L4 = MFMA16(pf0, onesf, L4);    L4 = MFMA16(pf1, onesf, L4);
    }

    const size_t obase = ((size_t)(b * N_ + q0 + quad * 4)) * D_ + h * DH_ + l15;
#pragma unroll
    for (int r = 0; r < 4; r++) {
        float inv = 1.0f / L4[r];
        unsigned short* orow = &o[obase + (size_t)r * D_];
        orow[0]  = f2bf_raw(O0[r] * inv);
        orow[16] = f2bf_raw(O1[r] * inv);
        orow[32] = f2bf_raw(O2[r] * inv);
        orow[48] = f2bf_raw(O3[r] * inv);
    }
}

// ---------- host ----------
extern "C" void kernel_launch(void* const* d_in, const int* in_sizes, int n_in,
                              void* d_out, int out_size, void* d_ws, size_t ws_size,
                              hipStream_t stream) {
    const float* x_in  = (const float*)d_in[0];
    const float* ctx_in= (const float*)d_in[1];
    const float* w1q = (const float*)d_in[2];
    const float* w1k = (const float*)d_in[3];
    const float* w1v = (const float*)d_in[4];
    const float* w1o = (const float*)d_in[5];
    const float* b1o = (const float*)d_in[6];
    const float* w2q = (const float*)d_in[7];
    const float* w2k = (const float*)d_in[8];
    const float* w2v = (const float*)d_in[9];
    const float* w2o = (const float*)d_in[10];
    const float* b2o = (const float*)d_in[11];
    const float* ln1g= (const float*)d_in[12];
    const float* ln1b= (const float*)d_in[13];
    const float* ln2g= (const float*)d_in[14];
    const float* ln2b= (const float*)d_in[15];
    const float* ln3g= (const float*)d_in[16];
    const float* ln3b= (const float*)d_in[17];
    const float* ffw1= (const float*)d_in[18];
    const float* ffb1= (const float*)d_in[19];
    const float* ffw2= (const float*)d_in[20];
    const float* ffb2= (const float*)d_in[21];
    float* out_f = (float*)d_out;

    char* ws = (char*)d_ws;
    unsigned short* wqkvT = (unsigned short*)(ws);
    unsigned short* w1oT  = (unsigned short*)(ws + (size_t)( 6 << 20));
    unsigned short* w2qT  = (unsigned short*)(ws + (size_t)( 8 << 20));
    unsigned short* w2oT  = (unsigned short*)(ws + (size_t)(10 << 20));
    unsigned short* ffw1T = (unsigned short*)(ws + (size_t)(12 << 20));
    unsigned short* ffw2T = (unsigned short*)(ws + (size_t)(28 << 20));
    float*          xbuf  = (float*)         (ws + (size_t)(36 << 20));
    unsigned short* h     = (unsigned short*)(ws + (size_t)(52 << 20));
    unsigned short* qb    = (unsigned short*)(ws + (size_t)(60 << 20));
    unsigned short* kb    = (unsigned short*)(ws + (size_t)(68 << 20));
    unsigned short* vTb   = (unsigned short*)(ws + (size_t)(76 << 20));
    unsigned short* vb    = (unsigned short*)(ws + (size_t)(84 << 20));  // = ob
    unsigned short* g     = (unsigned short*)(ws + (size_t)(60 << 20));

    const int MT = B_ * N_;

    auto wt = [&](const float* src, unsigned short* dst, int K, int N) {
        hipLaunchKernelGGL(wtrans_k, dim3(N / 64, K / 64), dim3(256), 0, stream, src, dst, K, N);
    };
    auto gmm = [&](const unsigned short* A, const unsigned short* BT,
                   const float* bias, const float* res, float* outf,
                   unsigned short* oq, unsigned short* ok, unsigned short* ov,
                   int M, int N, int K, int mode) {
        hipLaunchKernelGGL(gemm_mfma_k, dim3(N / 128, M / 128), dim3(256), 0, stream,
                           A, BT, bias, res, outf, oq, ok, ov, M, N, K, mode);
    };

    // weight transposes (bf16, W^T layout)
    wt(w1q, wqkvT,                 D_, D_);
    wt(w1k, wqkvT + (1024 * 1024), D_, D_);
    wt(w1v, wqkvT + (2048 * 1024), D_, D_);
    wt(w1o, w1oT, D_, D_);
    wt(w2q, w2qT, D_, D_);
    wt(w2o, w2oT, D_, D_);
    wt(ffw1, ffw1T, D_, 2 * FF_);
    wt(ffw2, ffw2T, FF_, D_);

    // ---- self attention ----
    hipLaunchKernelGGL(ln_k, dim3(MT), dim3(256), 0, stream, x_in, ln1g, ln1b, h);
    gmm(h, wqkvT, nullptr, nullptr, nullptr, qb, kb, vb, MT, 3072, D_, 0);
    hipLaunchKernelGGL(vtrans_k, dim3(B_ * H_, N_ / 64), dim3(256), 0, stream,
                       vb, vTb, N_, N_, N_);
    hipLaunchKernelGGL(flash_mfma_k, dim3(B_ * H_, N_ / 64), dim3(256), 0, stream,
                       qb, kb, vTb, vb /*=ob*/, N_, N_, N_, N_ / 64);
    gmm(vb /*=ob*/, w1oT, b1o, x_in, xbuf, nullptr, nullptr, nullptr, MT, D_, D_, 1);

    // ---- cross attention (n_kv = 77, padded to 128) ----
    hipLaunchKernelGGL(ln_k, dim3(MT), dim3(256), 0, stream, xbuf, ln2g, ln2b, h);
    gmm(h, w2qT, nullptr, nullptr, nullptr, qb, qb, qb, MT, D_, D_, 0);
    hipLaunchKernelGGL(gemm_k, dim3(D_ / 64, 3), dim3(256), 0, stream,
                       ctx_in, w2k, kb, B_ * NC_, D_, DC_);
    hipLaunchKernelGGL(gemm_k, dim3(D_ / 64, 3), dim3(256), 0, stream,
                       ctx_in, w2v, vb, B_ * NC_, D_, DC_);
    hipLaunchKernelGGL(vtrans_k, dim3(B_ * H_, 2), dim3(256), 0, stream,
                       vb, vTb, NC_, NC_, 128);
    hipLaunchKernelGGL(flash_mfma_k, dim3(B_ * H_, N_ / 64), dim3(256), 0, stream,
                       qb, kb, vTb, vb /*=ob*/, NC_, NC_, 128, 2);
    gmm(vb /*=ob*/, w2oT, b2o, xbuf, xbuf, nullptr, nullptr, nullptr, MT, D_, D_, 1);

    // ---- feed-forward (GEGLU) ----
    hipLaunchKernelGGL(ln_k, dim3(MT), dim3(256), 0, stream, xbuf, ln3g, ln3b, h);
    hipLaunchKernelGGL(geglu_mfma_k, dim3(FF_ / 128, MT / 128), dim3(256), 0, stream,
                       h, ffw1T, ffb1, g, MT, D_);
    gmm(g, ffw2T, ffb2, xbuf, out_f, nullptr, nullptr, nullptr, MT, D_, FF_, 1);
}

// Round 8
// 898.900 us; speedup vs baseline: 5.8738x; 1.0930x over previous
//
#include <hip/hip_runtime.h>
#include <hip/hip_bf16.h>
#include <math.h>

// Problem constants
#define B_    2
#define N_    2048
#define D_    1024
#define NC_   77
#define DC_   768
#define H_    16
#define DH_   64
#define FF_   4096
#define EPS_  1e-5f
#define SCALE_ 0.125f   // DH^-0.5
#define NEG_BIG -1e30f

typedef __attribute__((ext_vector_type(8))) short short8;   // 8 bf16 in 4 VGPRs
typedef __attribute__((ext_vector_type(4))) float f32x4;
#define MFMA16(a, b, c) __builtin_amdgcn_mfma_f32_16x16x32_bf16(a, b, c, 0, 0, 0)

// ---------- helpers ----------
static __device__ __forceinline__ unsigned short f2bf_raw(float f) {
    union { float f; unsigned int i; } x; x.f = f;
    unsigned int r = x.i + 0x7fffu + ((x.i >> 16) & 1u);   // RNE
    return (unsigned short)(r >> 16);
}

// async global->LDS, 16B per lane; LDS dest = wave-uniform base + lane*16
static __device__ __forceinline__ void gload16(const void* g, void* l) {
    __builtin_amdgcn_global_load_lds(
        (const __attribute__((address_space(1))) void*)g,
        (__attribute__((address_space(3))) void*)l, 16, 0, 0);
}

// ---------- weight transpose: src f32 [K][N] -> dst bf16 [N][K] ----------
__global__ __launch_bounds__(256) void wtrans_k(const float* __restrict__ src,
                                                unsigned short* __restrict__ dst,
                                                int K, int N) {
    __shared__ unsigned short t[64][68];
    const int k0 = blockIdx.y * 64, n0 = blockIdx.x * 64;
    const int rr = threadIdx.x >> 4;
    const int cc = (threadIdx.x & 15) * 4;
#pragma unroll
    for (int p = 0; p < 4; p++) {
        int k = rr + p * 16;
        float4 vd = *(const float4*)&src[(size_t)(k0 + k) * N + n0 + cc];
        t[k][cc + 0] = f2bf_raw(vd.x); t[k][cc + 1] = f2bf_raw(vd.y);
        t[k][cc + 2] = f2bf_raw(vd.z); t[k][cc + 3] = f2bf_raw(vd.w);
    }
    __syncthreads();
#pragma unroll
    for (int p = 0; p < 4; p++) {
        int n = rr + p * 16;
        ushort4 o;
        o.x = t[cc + 0][n]; o.y = t[cc + 1][n];
        o.z = t[cc + 2][n]; o.w = t[cc + 3][n];
        *(ushort4*)&dst[(size_t)(n0 + n) * K + k0 + cc] = o;
    }
}

// ---------- LayerNorm over D=1024, bf16 out ----------
__global__ __launch_bounds__(256) void ln_k(const float* __restrict__ x,
                                            const float* __restrict__ g,
                                            const float* __restrict__ b,
                                            unsigned short* __restrict__ out) {
    int row = blockIdx.x;
    const float* xr = x + (size_t)row * D_;
    float v0[4]; float s = 0.f, sq = 0.f;
#pragma unroll
    for (int i = 0; i < 4; i++) {
        float t = xr[threadIdx.x + 256 * i];
        v0[i] = t; s += t; sq += t * t;
    }
#pragma unroll
    for (int off = 32; off; off >>= 1) {
        s  += __shfl_xor(s,  off);
        sq += __shfl_xor(sq, off);
    }
    __shared__ float rs[4], rq[4];
    int wave = threadIdx.x >> 6, lane = threadIdx.x & 63;
    if (lane == 0) { rs[wave] = s; rq[wave] = sq; }
    __syncthreads();
    s  = rs[0] + rs[1] + rs[2] + rs[3];
    sq = rq[0] + rq[1] + rq[2] + rq[3];
    float mu  = s * (1.f / D_);
    float var = sq * (1.f / D_) - mu * mu;
    float inv = rsqrtf(var + EPS_);
#pragma unroll
    for (int i = 0; i < 4; i++) {
        int c = threadIdx.x + 256 * i;
        out[(size_t)row * D_ + c] = f2bf_raw((v0[i] - mu) * inv * g[c] + b[c]);
    }
}

// ---------- MFMA GEMM 128x128x32 (QKV fused / GEGLU-size grids) ----------
__global__ __launch_bounds__(256) void gemm_mfma_k(
        const unsigned short* __restrict__ A,
        const unsigned short* __restrict__ BT,
        const float* __restrict__ bias,
        const float* __restrict__ res,
        float* __restrict__ outf,
        unsigned short* __restrict__ oq,
        unsigned short* __restrict__ ok,
        unsigned short* __restrict__ ov,
        int M, int N, int K, int mode) {
    __shared__ unsigned short As[128 * 32];
    __shared__ unsigned short Bs[128 * 32];
    const int tid = threadIdx.x;
    const int w = tid >> 6, lane = tid & 63, quad = lane >> 4, l15 = lane & 15;
    const int wm = w >> 1, wn = w & 1;
    const int m0 = blockIdx.y * 128, n0 = blockIdx.x * 128;
    const int srow = lane >> 2;
    const int schunk = lane & 3;
    const int kswz = (schunk ^ (srow & 3)) * 8;
    const int rdsw = (quad ^ (l15 & 3)) * 8;

    f32x4 acc[4][4] = {};
    for (int k0 = 0; k0 < K; k0 += 32) {
#pragma unroll
        for (int i = 0; i < 2; i++) {
            int r = (w * 2 + i) * 16;
            gload16(&A[(size_t)(m0 + r + srow) * K + k0 + kswz], &As[r * 32]);
            gload16(&BT[(size_t)(n0 + r + srow) * K + k0 + kswz], &Bs[r * 32]);
        }
        __syncthreads();
        short8 af[4], bf[4];
#pragma unroll
        for (int i = 0; i < 4; i++) {
            af[i] = *(const short8*)&As[(wm * 64 + i * 16 + l15) * 32 + rdsw];
            bf[i] = *(const short8*)&Bs[(wn * 64 + i * 16 + l15) * 32 + rdsw];
        }
#pragma unroll
        for (int i = 0; i < 4; i++)
#pragma unroll
            for (int j = 0; j < 4; j++)
                acc[i][j] = MFMA16(af[i], bf[j], acc[i][j]);
        __syncthreads();
    }
#pragma unroll
    for (int i = 0; i < 4; i++) {
#pragma unroll
        for (int r = 0; r < 4; r++) {
            const int row = m0 + wm * 64 + i * 16 + quad * 4 + r;
#pragma unroll
            for (int j = 0; j < 4; j++) {
                const int col = n0 + wn * 64 + j * 16 + l15;
                float c = acc[i][j][r];
                if (mode == 0) {
                    int which = col >> 10, cc = col & 1023;
                    unsigned short* dst = which == 0 ? oq : (which == 1 ? ok : ov);
                    dst[(size_t)row * 1024 + cc] = f2bf_raw(which == 0 ? c * SCALE_ : c);
                } else {
                    outf[(size_t)row * N + col] =
                        c + bias[col] + res[(size_t)row * N + col];
                }
            }
        }
    }
}

// ---------- MFMA GEMM 64x64x64 (high-occupancy path for N=1024 GEMMs) ----------
// mode 0: bf16 out * scale; mode 1: f32 out = acc + bias + res.
__global__ __launch_bounds__(256) void gemm64_k(
        const unsigned short* __restrict__ A,
        const unsigned short* __restrict__ BT,
        const float* __restrict__ bias,
        const float* __restrict__ res,
        float* __restrict__ outf,
        unsigned short* __restrict__ outb,
        float scale,
        int M, int N, int K, int mode) {
    __shared__ unsigned short As[64 * 64];
    __shared__ unsigned short Bs[64 * 64];
    const int tid = threadIdx.x;
    const int w = tid >> 6, lane = tid & 63, quad = lane >> 4, l15 = lane & 15;
    const int wm = w >> 1, wn = w & 1;
    const int m0 = blockIdx.y * 64, n0 = blockIdx.x * 64;
    const int sr8 = lane >> 3;        // 0..7 row within 8-row stage group
    const int sc8 = lane & 7;         // chunk slot 0..7

    f32x4 acc[2][2] = {};
    for (int k0 = 0; k0 < K; k0 += 64) {
#pragma unroll
        for (int i = 0; i < 2; i++) {
            int row = w * 16 + i * 8 + sr8;
            int gch = sc8 ^ (row & 7);                  // chunk swizzle
            gload16(&A[(size_t)(m0 + row) * K + k0 + gch * 8], &As[(w * 16 + i * 8) * 64]);
            gload16(&BT[(size_t)(n0 + row) * K + k0 + gch * 8], &Bs[(w * 16 + i * 8) * 64]);
        }
        __syncthreads();
        short8 af[2][2], bf[2][2];
#pragma unroll
        for (int ii = 0; ii < 2; ii++) {
            int ra = wm * 32 + ii * 16 + l15;
            int rb = wn * 32 + ii * 16 + l15;
#pragma unroll
            for (int kh = 0; kh < 2; kh++) {
                int ca = (kh * 4 + quad) ^ (ra & 7);
                int cb = (kh * 4 + quad) ^ (rb & 7);
                af[ii][kh] = *(const short8*)&As[ra * 64 + ca * 8];
                bf[ii][kh] = *(const short8*)&Bs[rb * 64 + cb * 8];
            }
        }
#pragma unroll
        for (int ii = 0; ii < 2; ii++)
#pragma unroll
            for (int jj = 0; jj < 2; jj++) {
                acc[ii][jj] = MFMA16(af[ii][0], bf[jj][0], acc[ii][jj]);
                acc[ii][jj] = MFMA16(af[ii][1], bf[jj][1], acc[ii][jj]);
            }
        __syncthreads();
    }
#pragma unroll
    for (int ii = 0; ii < 2; ii++) {
#pragma unroll
        for (int r = 0; r < 4; r++) {
            const int row = m0 + wm * 32 + ii * 16 + quad * 4 + r;
#pragma unroll
            for (int jj = 0; jj < 2; jj++) {
                const int col = n0 + wn * 32 + jj * 16 + l15;
                float c = acc[ii][jj][r];
                if (mode == 0) {
                    outb[(size_t)row * N + col] = f2bf_raw(c * scale);
                } else {
                    outf[(size_t)row * N + col] =
                        c + bias[col] + res[(size_t)row * N + col];
                }
            }
        }
    }
}

// ---------- MFMA GEGLU ----------
__global__ __launch_bounds__(256) void geglu_mfma_k(
        const unsigned short* __restrict__ A,
        const unsigned short* __restrict__ BT,
        const float* __restrict__ bias,
        unsigned short* __restrict__ outg,
        int M, int K) {
    __shared__ unsigned short As[128 * 32];
    __shared__ unsigned short Bv[128 * 32];
    __shared__ unsigned short Bg[128 * 32];
    const int tid = threadIdx.x;
    const int w = tid >> 6, lane = tid & 63, quad = lane >> 4, l15 = lane & 15;
    const int wm = w >> 1, wn = w & 1;
    const int m0 = blockIdx.y * 128, n0 = blockIdx.x * 128;
    const int srow = lane >> 2;
    const int schunk = lane & 3;
    const int kswz = (schunk ^ (srow & 3)) * 8;
    const int rdsw = (quad ^ (l15 & 3)) * 8;

    f32x4 accv[4][4] = {}, accg[4][4] = {};
    for (int k0 = 0; k0 < K; k0 += 32) {
#pragma unroll
        for (int i = 0; i < 2; i++) {
            int r = (w * 2 + i) * 16;
            gload16(&A[(size_t)(m0 + r + srow) * K + k0 + kswz], &As[r * 32]);
            gload16(&BT[(size_t)(n0 + r + srow) * K + k0 + kswz], &Bv[r * 32]);
            gload16(&BT[(size_t)(FF_ + n0 + r + srow) * K + k0 + kswz], &Bg[r * 32]);
        }
        __syncthreads();
        short8 af[4], bvf[4], bgf[4];
#pragma unroll
        for (int i = 0; i < 4; i++) {
            af[i]  = *(const short8*)&As[(wm * 64 + i * 16 + l15) * 32 + rdsw];
            bvf[i] = *(const short8*)&Bv[(wn * 64 + i * 16 + l15) * 32 + rdsw];
            bgf[i] = *(const short8*)&Bg[(wn * 64 + i * 16 + l15) * 32 + rdsw];
        }
#pragma unroll
        for (int i = 0; i < 4; i++)
#pragma unroll
            for (int j = 0; j < 4; j++) {
                accv[i][j] = MFMA16(af[i], bvf[j], accv[i][j]);
                accg[i][j] = MFMA16(af[i], bgf[j], accg[i][j]);
            }
        __syncthreads();
    }
#pragma unroll
    for (int i = 0; i < 4; i++) {
#pragma unroll
        for (int r = 0; r < 4; r++) {
            const int row = m0 + wm * 64 + i * 16 + quad * 4 + r;
#pragma unroll
            for (int j = 0; j < 4; j++) {
                const int col = n0 + wn * 64 + j * 16 + l15;
                float vv = accv[i][j][r] + bias[col];
                float gg = accg[i][j][r] + bias[col + FF_];
                float ge = 0.5f * gg * (1.f + erff(gg * 0.70710678118654752f));
                outg[(size_t)row * FF_ + col] = f2bf_raw(vv * ge);
            }
        }
    }
}

// ---------- old f32 GEMM (tiny ctx K/V: M=154) ----------
__global__ __launch_bounds__(256) void gemm_k(const float* __restrict__ A,
                                              const float* __restrict__ W,
                                              unsigned short* __restrict__ outb,
                                              int M, int N, int K) {
    __shared__ float As[16][64];
    __shared__ float Ws[16][64];
    const int tx = threadIdx.x & 15;
    const int ty = threadIdx.x >> 4;
    const int m0 = blockIdx.y * 64, n0 = blockIdx.x * 64;
    const int lm = threadIdx.x >> 2;
    const int lk = (threadIdx.x & 3) * 4;
    const int wr = threadIdx.x >> 4;
    const int wc = (threadIdx.x & 15) * 4;
    float acc[4][4] = {};
    for (int k0 = 0; k0 < K; k0 += 16) {
        float4 av = make_float4(0.f, 0.f, 0.f, 0.f);
        if (m0 + lm < M) av = *(const float4*)&A[(size_t)(m0 + lm) * K + k0 + lk];
        float4 wv = *(const float4*)&W[(size_t)(k0 + wr) * N + n0 + wc];
        As[lk + 0][lm] = av.x; As[lk + 1][lm] = av.y;
        As[lk + 2][lm] = av.z; As[lk + 3][lm] = av.w;
        *(float4*)&Ws[wr][wc] = wv;
        __syncthreads();
#pragma unroll
        for (int kk = 0; kk < 16; kk++) {
            float4 a = *(const float4*)&As[kk][ty * 4];
            float4 b = *(const float4*)&Ws[kk][tx * 4];
            float ar[4] = { a.x, a.y, a.z, a.w };
            float br[4] = { b.x, b.y, b.z, b.w };
#pragma unroll
            for (int i = 0; i < 4; i++)
#pragma unroll
                for (int j = 0; j < 4; j++)
                    acc[i][j] = fmaf(ar[i], br[j], acc[i][j]);
        }
        __syncthreads();
    }
#pragma unroll
    for (int i = 0; i < 4; i++) {
        int row = m0 + ty * 4 + i;
        if (row >= M) continue;
        ushort4 u;
        u.x = f2bf_raw(acc[i][0]); u.y = f2bf_raw(acc[i][1]);
        u.z = f2bf_raw(acc[i][2]); u.w = f2bf_raw(acc[i][3]);
        *(ushort4*)&outb[(size_t)row * N + n0 + tx * 4] = u;
    }
}

// ---------- V transpose ----------
__global__ __launch_bounds__(256) void vtrans_k(const unsigned short* __restrict__ v,
                                                unsigned short* __restrict__ vT,
                                                int ntok, int tokrows, int npad) {
    __shared__ unsigned short tile[64][68];
    const int bh = blockIdx.x, b = bh >> 4, h = bh & 15;
    const int t0 = blockIdx.y * 64;
    const int tt = threadIdx.x >> 4;
    const int dg = (threadIdx.x & 15) * 4;
#pragma unroll
    for (int p = 0; p < 4; p++) {
        int tok = t0 + tt + 16 * p;
        ushort4 val = make_ushort4(0, 0, 0, 0);
        if (tok < ntok)
            val = *(const ushort4*)&v[((size_t)(b * tokrows + tok)) * D_ + h * DH_ + dg];
        *(ushort4*)&tile[tt + 16 * p][dg] = val;
    }
    __syncthreads();
#pragma unroll
    for (int p = 0; p < 4; p++) {
        int d = tt + 16 * p;
        ushort4 w;
        w.x = tile[dg + 0][d]; w.y = tile[dg + 1][d];
        w.z = tile[dg + 2][d]; w.w = tile[dg + 3][d];
        *(ushort4*)&vT[((size_t)(bh * 64 + d)) * npad + t0 + dg] = w;
    }
}

// ---------- MFMA flash attention v3: split-KV across the 4 waves, LDS merge ----------
// Block = 16 query rows; wave w handles tiles t = w, w+4, ...; merge (m,l,O) at end.
__global__ __launch_bounds__(256) void flash_mfma_k(const unsigned short* __restrict__ qb,
                                                    const unsigned short* __restrict__ kb,
                                                    const unsigned short* __restrict__ vT,
                                                    unsigned short* __restrict__ o,
                                                    int n_kv, int kv_rows, int npadv, int ntiles) {
    __shared__ unsigned short Pls[4][16][72];
    __shared__ float OLs[3][16][64];
    __shared__ float mls[3][16][2];
    const int bh = blockIdx.x, b = bh >> 4, h = bh & 15;
    const int w = threadIdx.x >> 6;
    const int lane = threadIdx.x & 63, quad = lane >> 4, l15 = lane & 15;
    const int q0 = blockIdx.y * 16;

    const size_t qoff = ((size_t)(b * N_ + q0 + l15)) * D_ + h * DH_ + quad * 8;
    const short8 qf0 = *(const short8*)&qb[qoff];
    const short8 qf1 = *(const short8*)&qb[qoff + 32];

    short8 onesf;
#pragma unroll
    for (int i = 0; i < 8; i++) onesf[i] = (short)0x3F80;   // bf16 1.0

    f32x4 O0 = {0.f, 0.f, 0.f, 0.f}, O1 = O0, O2 = O0, O3 = O0, L4 = O0;
    f32x4 m4 = {NEG_BIG, NEG_BIG, NEG_BIG, NEG_BIG};

    const unsigned short* vbase = vT + (size_t)(bh * 64) * npadv;

    for (int t = w; t < ntiles; t += 4) {
        const int j0 = t * 64;
        short8 kf[4][2];
#pragma unroll
        for (int cb = 0; cb < 4; cb++) {
            const size_t kr = ((size_t)(b * kv_rows + j0 + 16 * cb + l15)) * D_ + h * DH_ + quad * 8;
            kf[cb][0] = *(const short8*)&kb[kr];
            kf[cb][1] = *(const short8*)&kb[kr + 32];
        }
        short8 vf[4][2];
#pragma unroll
        for (int n = 0; n < 4; n++) {
            const size_t vr = (size_t)(l15 + 16 * n) * npadv + j0 + quad * 8;
            vf[n][0] = *(const short8*)&vbase[vr];
            vf[n][1] = *(const short8*)&vbase[vr + 32];
        }

        f32x4 s[4];
#pragma unroll
        for (int cb = 0; cb < 4; cb++) {
            f32x4 z = {0.f, 0.f, 0.f, 0.f};
            z = MFMA16(qf0, kf[cb][0], z);
            z = MFMA16(qf1, kf[cb][1], z);
            s[cb] = z;
        }
#pragma unroll
        for (int cb = 0; cb < 4; cb++)
            if (j0 + 16 * cb + l15 >= n_kv) {
                s[cb][0] = NEG_BIG; s[cb][1] = NEG_BIG;
                s[cb][2] = NEG_BIG; s[cb][3] = NEG_BIG;
            }

        f32x4 t4;
#pragma unroll
        for (int r = 0; r < 4; r++)
            t4[r] = fmaxf(fmaxf(s[0][r], s[1][r]), fmaxf(s[2][r], s[3][r]));
#pragma unroll
        for (int off = 1; off < 16; off <<= 1) {
#pragma unroll
            for (int r = 0; r < 4; r++) t4[r] = fmaxf(t4[r], __shfl_xor(t4[r], off));
        }
        f32x4 mn, al;
#pragma unroll
        for (int r = 0; r < 4; r++) {
            mn[r] = fmaxf(m4[r], t4[r]);
            al[r] = __expf(m4[r] - mn[r]);
            m4[r] = mn[r];
        }
#pragma unroll
        for (int cb = 0; cb < 4; cb++) {
#pragma unroll
            for (int r = 0; r < 4; r++)
                Pls[w][quad * 4 + r][l15 + 16 * cb] = f2bf_raw(__expf(s[cb][r] - mn[r]));
        }
#pragma unroll
        for (int r = 0; r < 4; r++) {
            O0[r] *= al[r]; O1[r] *= al[r]; O2[r] *= al[r]; O3[r] *= al[r];
            L4[r] *= al[r];
        }
        const short8 pf0 = *(const short8*)&Pls[w][l15][quad * 8];
        const short8 pf1 = *(const short8*)&Pls[w][l15][32 + quad * 8];

        O0 = MFMA16(pf0, vf[0][0], O0); O0 = MFMA16(pf1, vf[0][1], O0);
        O1 = MFMA16(pf0, vf[1][0], O1); O1 = MFMA16(pf1, vf[1][1], O1);
        O2 = MFMA16(pf0, vf[2][0], O2); O2 = MFMA16(pf1, vf[2][1], O2);
        O3 = MFMA16(pf0, vf[3][0], O3); O3 = MFMA16(pf1, vf[3][1], O3);
        L4 = MFMA16(pf0, onesf, L4);    L4 = MFMA16(pf1, onesf, L4);
    }

    // waves 1-3 publish partial state
    if (w > 0) {
#pragma unroll
        for (int r = 0; r < 4; r++) {
            int row = quad * 4 + r;
            OLs[w - 1][row][l15]      = O0[r];
            OLs[w - 1][row][l15 + 16] = O1[r];
            OLs[w - 1][row][l15 + 32] = O2[r];
            OLs[w - 1][row][l15 + 48] = O3[r];
            if (l15 == 0) { mls[w - 1][row][0] = m4[r]; mls[w - 1][row][1] = L4[r]; }
        }
    }
    __syncthreads();
    if (w == 0) {
        const size_t obase = ((size_t)(b * N_ + q0 + quad * 4)) * D_ + h * DH_ + l15;
#pragma unroll
        for (int r = 0; r < 4; r++) {
            int row = quad * 4 + r;
            float mstar = m4[r];
#pragma unroll
            for (int w2 = 0; w2 < 3; w2++) mstar = fmaxf(mstar, mls[w2][row][0]);
            float a0 = __expf(m4[r] - mstar);
            float lt = L4[r] * a0;
            float o0 = O0[r] * a0, o1 = O1[r] * a0, o2 = O2[r] * a0, o3 = O3[r] * a0;
#pragma unroll
            for (int w2 = 0; w2 < 3; w2++) {
                float aw = __expf(mls[w2][row][0] - mstar);
                lt += mls[w2][row][1] * aw;
                o0 += OLs[w2][row][l15]      * aw;
                o1 += OLs[w2][row][l15 + 16] * aw;
                o2 += OLs[w2][row][l15 + 32] * aw;
                o3 += OLs[w2][row][l15 + 48] * aw;
            }
            float inv = 1.0f / lt;
            unsigned short* orow = &o[obase + (size_t)r * D_];
            orow[0]  = f2bf_raw(o0 * inv);
            orow[16] = f2bf_raw(o1 * inv);
            orow[32] = f2bf_raw(o2 * inv);
            orow[48] = f2bf_raw(o3 * inv);
        }
    }
}

// ---------- host ----------
extern "C" void kernel_launch(void* const* d_in, const int* in_sizes, int n_in,
                              void* d_out, int out_size, void* d_ws, size_t ws_size,
                              hipStream_t stream) {
    const float* x_in  = (const float*)d_in[0];
    const float* ctx_in= (const float*)d_in[1];
    const float* w1q = (const float*)d_in[2];
    const float* w1k = (const float*)d_in[3];
    const float* w1v = (const float*)d_in[4];
    const float* w1o = (const float*)d_in[5];
    const float* b1o = (const float*)d_in[6];
    const float* w2q = (const float*)d_in[7];
    const float* w2k = (const float*)d_in[8];
    const float* w2v = (const float*)d_in[9];
    const float* w2o = (const float*)d_in[10];
    const float* b2o = (const float*)d_in[11];
    const float* ln1g= (const float*)d_in[12];
    const float* ln1b= (const float*)d_in[13];
    const float* ln2g= (const float*)d_in[14];
    const float* ln2b= (const float*)d_in[15];
    const float* ln3g= (const float*)d_in[16];
    const float* ln3b= (const float*)d_in[17];
    const float* ffw1= (const float*)d_in[18];
    const float* ffb1= (const float*)d_in[19];
    const float* ffw2= (const float*)d_in[20];
    const float* ffb2= (const float*)d_in[21];
    float* out_f = (float*)d_out;

    char* ws = (char*)d_ws;
    unsigned short* wqkvT = (unsigned short*)(ws);
    unsigned short* w1oT  = (unsigned short*)(ws + (size_t)( 6 << 20));
    unsigned short* w2qT  = (unsigned short*)(ws + (size_t)( 8 << 20));
    unsigned short* w2oT  = (unsigned short*)(ws + (size_t)(10 << 20));
    unsigned short* ffw1T = (unsigned short*)(ws + (size_t)(12 << 20));
    unsigned short* ffw2T = (unsigned short*)(ws + (size_t)(28 << 20));
    float*          xbuf  = (float*)         (ws + (size_t)(36 << 20));
    unsigned short* h     = (unsigned short*)(ws + (size_t)(52 << 20));
    unsigned short* qb    = (unsigned short*)(ws + (size_t)(60 << 20));
    unsigned short* kb    = (unsigned short*)(ws + (size_t)(68 << 20));
    unsigned short* vTb   = (unsigned short*)(ws + (size_t)(76 << 20));
    unsigned short* vb    = (unsigned short*)(ws + (size_t)(84 << 20));  // = ob
    unsigned short* g     = (unsigned short*)(ws + (size_t)(60 << 20));

    const int MT = B_ * N_;

    auto wt = [&](const float* src, unsigned short* dst, int K, int N) {
        hipLaunchKernelGGL(wtrans_k, dim3(N / 64, K / 64), dim3(256), 0, stream, src, dst, K, N);
    };
    auto gmm = [&](const unsigned short* A, const unsigned short* BT,
                   const float* bias, const float* res, float* outf,
                   unsigned short* oq, unsigned short* ok, unsigned short* ov,
                   int M, int N, int K, int mode) {
        hipLaunchKernelGGL(gemm_mfma_k, dim3(N / 128, M / 128), dim3(256), 0, stream,
                           A, BT, bias, res, outf, oq, ok, ov, M, N, K, mode);
    };
    auto g64 = [&](const unsigned short* A, const unsigned short* BT,
                   const float* bias, const float* res, float* outf,
                   unsigned short* outb, float scale, int M, int N, int K, int mode) {
        hipLaunchKernelGGL(gemm64_k, dim3(N / 64, M / 64), dim3(256), 0, stream,
                           A, BT, bias, res, outf, outb, scale, M, N, K, mode);
    };

    // weight transposes (bf16, W^T layout)
    wt(w1q, wqkvT,                 D_, D_);
    wt(w1k, wqkvT + (1024 * 1024), D_, D_);
    wt(w1v, wqkvT + (2048 * 1024), D_, D_);
    wt(w1o, w1oT, D_, D_);
    wt(w2q, w2qT, D_, D_);
    wt(w2o, w2oT, D_, D_);
    wt(ffw1, ffw1T, D_, 2 * FF_);
    wt(ffw2, ffw2T, FF_, D_);

    // ---- self attention ----
    hipLaunchKernelGGL(ln_k, dim3(MT), dim3(256), 0, stream, x_in, ln1g, ln1b, h);
    gmm(h, wqkvT, nullptr, nullptr, nullptr, qb, kb, vb, MT, 3072, D_, 0);
    hipLaunchKernelGGL(vtrans_k, dim3(B_ * H_, N_ / 64), dim3(256), 0, stream,
                       vb, vTb, N_, N_, N_);
    hipLaunchKernelGGL(flash_mfma_k, dim3(B_ * H_, N_ / 16), dim3(256), 0, stream,
                       qb, kb, vTb, vb /*=ob*/, N_, N_, N_, N_ / 64);
    g64(vb /*=ob*/, w1oT, b1o, x_in, xbuf, nullptr, 1.0f, MT, D_, D_, 1);

    // ---- cross attention (n_kv = 77, padded to 128) ----
    hipLaunchKernelGGL(ln_k, dim3(MT), dim3(256), 0, stream, xbuf, ln2g, ln2b, h);
    g64(h, w2qT, nullptr, nullptr, nullptr, qb, SCALE_, MT, D_, D_, 0);
    hipLaunchKernelGGL(gemm_k, dim3(D_ / 64, 3), dim3(256), 0, stream,
                       ctx_in, w2k, kb, B_ * NC_, D_, DC_);
    hipLaunchKernelGGL(gemm_k, dim3(D_ / 64, 3), dim3(256), 0, stream,
                       ctx_in, w2v, vb, B_ * NC_, D_, DC_);
    hipLaunchKernelGGL(vtrans_k, dim3(B_ * H_, 2), dim3(256), 0, stream,
                       vb, vTb, NC_, NC_, 128);
    hipLaunchKernelGGL(flash_mfma_k, dim3(B_ * H_, N_ / 16), dim3(256), 0, stream,
                       qb, kb, vTb, vb /*=ob*/, NC_, NC_, 128, 2);
    g64(vb /*=ob*/, w2oT, b2o, xbuf, xbuf, nullptr, 1.0f, MT, D_, D_, 1);

    // ---- feed-forward (GEGLU) ----
    hipLaunchKernelGGL(ln_k, dim3(MT), dim3(256), 0, stream, xbuf, ln3g, ln3b, h);
    hipLaunchKernelGGL(geglu_mfma_k, dim3(FF_ / 128, MT / 128), dim3(256), 0, stream,
                       h, ffw1T, ffb1, g, MT, D_);
    g64(g, ffw2T, ffb2, xbuf, out_f, nullptr, 1.0f, MT, D_, FF_, 1);
}